// Round 1
// baseline (780.709 us; speedup 1.0000x reference)
//
#include <hip/hip_runtime.h>

#define NF 4
#define NV 4
#define NE 64
#define NIND 1024
#define NOUTD 1024
#define MM 1026
#define FV 16
#define BK 32

// ws float offsets
#define WS_THETA 0
#define WS_GT    (MM * NOUTD)
#define WS_S     (2 * MM * NOUTD)
#define WS_GMIN  (WS_S + FV * NOUTD)
#define WS_BETA  (WS_GMIN + NOUTD)
#define WS_ALPHA (WS_BETA + MM)
#define POWER_IDX (NF * NV * NE * NOUTD)  // 1048576

// ---------------- init: zero S/power, init gmin, compute selectors ----------
__global__ __launch_bounds__(1024) void k_init(
    const float* __restrict__ coeff_act, const float* __restrict__ coeff_neg,
    const float* __restrict__ gum_act, const float* __restrict__ gum_neg,
    float* __restrict__ ws, float* __restrict__ out) {
  int t = threadIdx.x;
  for (int i = t; i < FV * NOUTD; i += 1024) ws[WS_S + i] = 0.f;
  if (t < NOUTD) {
    ((unsigned*)ws)[WS_GMIN + t] = 0x7F800000u;  // +inf
    float c0 = fminf(fmaxf(coeff_act[t], -1.f), 1.f);
    float c1 = fminf(fmaxf(coeff_act[NOUTD + t], -1.f), 1.f);
    ws[WS_ALPHA + t] = ((c1 + gum_act[NOUTD + t]) > (c0 + gum_act[t])) ? 1.f : 0.f;
  }
  for (int m = t; m < MM; m += 1024) {
    float c0 = fminf(fmaxf(coeff_neg[m], -1.f), 1.f);
    float c1 = fminf(fmaxf(coeff_neg[MM + m], -1.f), 1.f);
    ws[WS_BETA + m] = ((c1 + gum_neg[MM + m]) > (c0 + gum_neg[m])) ? 1.f : 0.f;
  }
  if (t == 0) out[POWER_IDX] = 0.f;
}

// ---------------- theta (forward value of ST-clip/zero) + per-col min |tc| --
__global__ __launch_bounds__(256) void k_theta_min(const float* __restrict__ theta_,
                                                   float* __restrict__ ws) {
  int n = blockIdx.x * 256 + threadIdx.x;
  int m0 = blockIdx.y * 129;
  int m1 = min(MM, m0 + 129);
  float lmin = __uint_as_float(0x7F800000u);
  for (int m = m0; m < m1; m++) {
    float t_ = theta_[m * NOUTD + n];
    float tc = fminf(fmaxf(t_, -1.f), 1.f);
    float gi = fabsf(tc);
    ws[WS_THETA + m * NOUTD + n] = (gi < 0.01f) ? 0.f : tc;
    lmin = fminf(lmin, gi);
  }
  atomicMin((unsigned*)ws + WS_GMIN + n, __float_as_uint(lmin));  // gi>=0: uint order ok
}

// ---------------- gt = |tc| * (PGMIN / colmin) ------------------------------
__global__ __launch_bounds__(256) void k_gt(const float* __restrict__ theta_,
                                            float* __restrict__ ws) {
  int n = blockIdx.x * 256 + threadIdx.x;
  int m0 = blockIdx.y * 129;
  int m1 = min(MM, m0 + 129);
  float s = 0.1f / __uint_as_float(((unsigned*)ws)[WS_GMIN + n]);
  for (int m = m0; m < m1; m++) {
    float tc = fminf(fmaxf(theta_[m * NOUTD + n], -1.f), 1.f);
    ws[WS_GT + m * NOUTD + n] = fabsf(tc) * s;
  }
}

// ---------------- S[f,v,n] = sum_m |tn| (partial + atomic) ------------------
__global__ __launch_bounds__(256) void k_s(const float* __restrict__ noise,
                                           const float* __restrict__ fault,
                                           float* __restrict__ ws) {
  int n = blockIdx.x * 256 + threadIdx.x;
  int fv = blockIdx.z, f = fv >> 2;
  int m0 = blockIdx.y * 257;
  int m1 = min(MM, m0 + 257);
  const float* __restrict__ np_ = noise + (size_t)fv * MM * NOUTD;
  const float* __restrict__ fp = fault + (size_t)f * MM * NOUTD;
  const float* __restrict__ tp = ws + WS_THETA;
  float s = 0.f;
  for (int m = m0; m < m1; m++) {
    float u = np_[(size_t)m * NOUTD + n];
    float fac = fmaf(u, 0.2f, 0.9f);
    s += fabsf(tp[m * NOUTD + n] * fac * fp[m * NOUTD + n]);
  }
  atomicAdd(ws + WS_S + fv * NOUTD + n, s);
}

// ---------------- staging helper: ax / an chunk into LDS --------------------
__device__ __forceinline__ void stage_A(const float* __restrict__ aslab,
                                        const float* __restrict__ beta,
                                        int mc, int tid,
                                        float axs[][68], float ans[][68]) {
#pragma unroll
  for (int l = 0; l < 4; l++) {
    int q = tid + l * 128;            // 0..511 : 64 e-rows x 8 float4-quads
    int e = q >> 3, mq = (q & 7) * 4;
    float4 av = *(const float4*)(aslab + e * NIND + mc + mq);
    float xs[4] = {av.x, av.y, av.z, av.w};
#pragma unroll
    for (int ii = 0; ii < 4; ii++) {
      int ml = mq + ii;
      float x = xs[ii];
      float bsel = beta[mc + ml];
      float anv = (bsel != 0.f) ? (1.f / (1.f + __expf(4.f * x - 2.f)))
                                : (1.f - x);
      axs[ml][e] = x;
      ans[ml][e] = anv;
    }
  }
}

// ---------------- fused main: z, activation, power --------------------------
__global__ __launch_bounds__(128) void k_main(
    const float* __restrict__ a, const float* __restrict__ noise,
    const float* __restrict__ fault, const float* __restrict__ ws,
    float* __restrict__ out) {
  const int tid = threadIdx.x;
  const int tn = tid & 7;    // n-group (4 n each)
  const int te = tid >> 3;   // 0..15   (4 e each)
  const int fv = blockIdx.y, f = fv >> 2;
  const int n0 = blockIdx.x * 32;
  const int nb = n0 + tn * 4;
  const int e0 = te * 4;
  const float* __restrict__ aslab = a + (size_t)fv * NE * NIND;
  const float* __restrict__ nslab = noise + (size_t)fv * MM * NOUTD;
  const float* __restrict__ fslab = fault + (size_t)f * MM * NOUTD;
  const float* __restrict__ theta = ws + WS_THETA;
  const float* __restrict__ gts = ws + WS_GT;
  const float* __restrict__ beta = ws + WS_BETA;

  __shared__ float axs[BK][68];
  __shared__ float ans[BK][68];
  __shared__ float wps[BK][32];
  __shared__ float wns[BK][32];
  __shared__ float red[128];

  float invs[4];
#pragma unroll
  for (int k = 0; k < 4; k++)
    invs[k] = 1.f / (ws[WS_S + fv * NOUTD + nb + k] + 1e-10f);
  const int wcol = tid & 31, wmr = tid >> 5;
  const float ivw = 1.f / (ws[WS_S + fv * NOUTD + n0 + wcol] + 1e-10f);

  float acc[4][4] = {};

  // ======== phase 1: z = ax@(W*pos) + an@(W*neg) ========
  for (int mc = 0; mc < 1024; mc += BK) {
    stage_A(aslab, beta, mc, tid, axs, ans);
#pragma unroll
    for (int j = 0; j < 8; j++) {
      int ml = wmr * 8 + j;
      int m = mc + ml;
      int n = n0 + wcol;
      float th = theta[m * NOUTD + n];
      float u = nslab[(size_t)m * NOUTD + n];
      float fl = fslab[m * NOUTD + n];
      float t = th * fmaf(u, 0.2f, 0.9f) * fl;
      float w = fabsf(t) * ivw;
      float wp = (t >= 0.f) ? w : 0.f;
      wps[ml][wcol] = wp;
      wns[ml][wcol] = w - wp;
    }
    __syncthreads();
#pragma unroll
    for (int j = 0; j < BK; j++) {
      float4 ax4 = *(const float4*)&axs[j][e0];
      float4 an4 = *(const float4*)&ans[j][e0];
      float4 wp4 = *(const float4*)&wps[j][tn * 4];
      float4 wn4 = *(const float4*)&wns[j][tn * 4];
      float ax[4] = {ax4.x, ax4.y, ax4.z, ax4.w};
      float an[4] = {an4.x, an4.y, an4.z, an4.w};
      float wp[4] = {wp4.x, wp4.y, wp4.z, wp4.w};
      float wn[4] = {wn4.x, wn4.y, wn4.z, wn4.w};
#pragma unroll
      for (int i = 0; i < 4; i++)
#pragma unroll
        for (int k = 0; k < 4; k++)
          acc[i][k] = fmaf(ax[i], wp[k], fmaf(an[i], wn[k], acc[i][k]));
    }
    __syncthreads();
  }
  // tail: m=1024 (ax=1, an=anb const); m=1025 (ax=an=0 -> no z contribution)
  const float anb = (beta[1024] != 0.f) ? (1.f / (1.f + __expf(2.f))) : 0.f;
#pragma unroll
  for (int k = 0; k < 4; k++) {
    int n = nb + k;
    float th = theta[1024 * NOUTD + n];
    float u = nslab[(size_t)1024 * NOUTD + n];
    float fl = fslab[1024 * NOUTD + n];
    float t = th * fmaf(u, 0.2f, 0.9f) * fl;
    float w = fabsf(t) * invs[k];
    float wp = (t >= 0.f) ? w : 0.f;
    float add = wp + (w - wp) * anb;
#pragma unroll
    for (int i = 0; i < 4; i++) acc[i][k] += add;
  }

  // ======== epilogue: a_new = alpha-selected activation ========
  float alv[4];
#pragma unroll
  for (int k = 0; k < 4; k++) alv[k] = ws[WS_ALPHA + nb + k];
#pragma unroll
  for (int i = 0; i < 4; i++) {
    float4 o;
    float* op = (float*)&o;
#pragma unroll
    for (int k = 0; k < 4; k++) {
      float z = acc[i][k];
      float s0 = 1.f / (1.f + __expf(2.f - 4.f * z));        // sigmoid(4(z-.5))
      float t1 = 1.f - 2.f / (__expf(2.f * z) + 1.f);        // tanh(z)
      op[k] = (alv[k] != 0.f) ? t1 : s0;
    }
    *(float4*)(out + (size_t)(fv * NE + e0 + i) * NOUTD + nb) = o;
  }

  // ======== phase 2: power = sum gt*(p*(ax-z)^2 + q*(an-z)^2)/(EVF) ========
  float szz[4];
#pragma unroll
  for (int k = 0; k < 4; k++)
    szz[k] = acc[0][k] * acc[0][k] + acc[1][k] * acc[1][k] +
             acc[2][k] * acc[2][k] + acc[3][k] * acc[3][k];
  float pacc = 0.f;
  for (int mc = 0; mc < 1024; mc += BK) {
    stage_A(aslab, beta, mc, tid, axs, ans);
#pragma unroll
    for (int j = 0; j < 8; j++) {
      int ml = wmr * 8 + j;
      int m = mc + ml;
      int n = n0 + wcol;
      float th = theta[m * NOUTD + n];
      float fl = fslab[m * NOUTD + n];
      float g = gts[m * NOUTD + n];
      bool p = (th * fl) >= 0.f;  // == sign(tn): noise factor > 0
      wps[ml][wcol] = p ? g : 0.f;
      wns[ml][wcol] = p ? 0.f : g;
    }
    __syncthreads();
#pragma unroll
    for (int j = 0; j < BK; j++) {
      float4 ax4 = *(const float4*)&axs[j][e0];
      float4 an4 = *(const float4*)&ans[j][e0];
      float4 gp4 = *(const float4*)&wps[j][tn * 4];
      float4 gq4 = *(const float4*)&wns[j][tn * 4];
      float ax[4] = {ax4.x, ax4.y, ax4.z, ax4.w};
      float an[4] = {an4.x, an4.y, an4.z, an4.w};
      float gp[4] = {gp4.x, gp4.y, gp4.z, gp4.w};
      float gq[4] = {gq4.x, gq4.y, gq4.z, gq4.w};
      float sa2 = ax[0] * ax[0] + ax[1] * ax[1] + ax[2] * ax[2] + ax[3] * ax[3];
      float sb2 = an[0] * an[0] + an[1] * an[1] + an[2] * an[2] + an[3] * an[3];
#pragma unroll
      for (int k = 0; k < 4; k++) {
        float dA = ax[0] * acc[0][k] + ax[1] * acc[1][k] +
                   ax[2] * acc[2][k] + ax[3] * acc[3][k];
        float dB = an[0] * acc[0][k] + an[1] * acc[1][k] +
                   an[2] * acc[2][k] + an[3] * acc[3][k];
        float tA = sa2 + szz[k] - 2.f * dA;
        float tB = sb2 + szz[k] - 2.f * dB;
        pacc += gp[k] * tA + gq[k] * tB;
      }
    }
    __syncthreads();
  }
  // power tail: m=1024 (sel = p?1:anb), m=1025 (sel=0 -> gt*z^2)
#pragma unroll
  for (int k = 0; k < 4; k++) {
    int n = nb + k;
    float th = theta[1024 * NOUTD + n];
    float fl = fslab[1024 * NOUTD + n];
    float g = gts[1024 * NOUTD + n];
    float sel = (th * fl >= 0.f) ? 1.f : anb;
#pragma unroll
    for (int i = 0; i < 4; i++) {
      float d = sel - acc[i][k];
      pacc = fmaf(g * d, d, pacc);
    }
    pacc = fmaf(gts[1025 * NOUTD + n], szz[k], pacc);
  }

  red[tid] = pacc;
  __syncthreads();
  for (int s = 64; s > 0; s >>= 1) {
    if (tid < s) red[tid] += red[tid + s];
    __syncthreads();
  }
  if (tid == 0) atomicAdd(out + POWER_IDX, red[0] * (1.f / 1024.f));
}

extern "C" void kernel_launch(void* const* d_in, const int* in_sizes, int n_in,
                              void* d_out, int out_size, void* d_ws, size_t ws_size,
                              hipStream_t stream) {
  const float* a = (const float*)d_in[0];
  const float* theta_ = (const float*)d_in[1];
  const float* coeff_act = (const float*)d_in[2];
  const float* coeff_neg = (const float*)d_in[3];
  const float* noise_u = (const float*)d_in[4];
  const float* gum_act = (const float*)d_in[5];
  const float* gum_neg = (const float*)d_in[6];
  const float* fault = (const float*)d_in[7];
  float* out = (float*)d_out;
  float* ws = (float*)d_ws;

  k_init<<<1, 1024, 0, stream>>>(coeff_act, coeff_neg, gum_act, gum_neg, ws, out);
  k_theta_min<<<dim3(4, 8), 256, 0, stream>>>(theta_, ws);
  k_gt<<<dim3(4, 8), 256, 0, stream>>>(theta_, ws);
  k_s<<<dim3(4, 4, 16), 256, 0, stream>>>(noise_u, fault, ws);
  k_main<<<dim3(32, 16), 128, 0, stream>>>(a, noise_u, fault, ws, out);
}

// Round 2
// 395.663 us; speedup vs baseline: 1.9732x; 1.9732x over previous
//
#include <hip/hip_runtime.h>

#define NE 64
#define NIND 1024
#define ND 1024
#define MM 1026
#define BK 32

// ws float offsets
#define WS_THETA 0
#define WS_GT    1050624
#define WS_GMINP 2101248
#define WS_SP    2134016
#define WS_GSUMP 2658304
#define WS_BETA  2691072
#define WS_ALPHA 2692100
#define POWER_IDX 1048576

__device__ __forceinline__ float frcp(float x) { return __builtin_amdgcn_rcpf(x); }

// ---- k_prep: theta forward value + per-chunk col-min + selectors + power=0 ----
__global__ __launch_bounds__(256) void k_prep(
    const float* __restrict__ theta_, const float* __restrict__ coeff_act,
    const float* __restrict__ coeff_neg, const float* __restrict__ gum_act,
    const float* __restrict__ gum_neg, float* __restrict__ ws,
    float* __restrict__ out) {
  int b = blockIdx.x, t = threadIdx.x;
  int n4 = t * 4;
  int m0 = b * 32, m1 = (b == 31) ? MM : m0 + 32;
  float mn0 = 1e30f, mn1 = 1e30f, mn2 = 1e30f, mn3 = 1e30f;
  for (int m = m0; m < m1; m++) {
    float4 tv = *(const float4*)(theta_ + m * ND + n4);
    float c0 = fminf(fmaxf(tv.x, -1.f), 1.f);
    float c1 = fminf(fmaxf(tv.y, -1.f), 1.f);
    float c2 = fminf(fmaxf(tv.z, -1.f), 1.f);
    float c3 = fminf(fmaxf(tv.w, -1.f), 1.f);
    float g0 = fabsf(c0), g1 = fabsf(c1), g2 = fabsf(c2), g3 = fabsf(c3);
    float4 o = {g0 < 0.01f ? 0.f : c0, g1 < 0.01f ? 0.f : c1,
                g2 < 0.01f ? 0.f : c2, g3 < 0.01f ? 0.f : c3};
    *(float4*)(ws + WS_THETA + m * ND + n4) = o;
    mn0 = fminf(mn0, g0); mn1 = fminf(mn1, g1);
    mn2 = fminf(mn2, g2); mn3 = fminf(mn3, g3);
  }
  float4 mo = {mn0, mn1, mn2, mn3};
  *(float4*)(ws + WS_GMINP + b * ND + n4) = mo;
  if (b == 0) {
#pragma unroll
    for (int k = 0; k < 4; k++) {
      int n = n4 + k;
      float c0 = fminf(fmaxf(coeff_act[n], -1.f), 1.f);
      float c1 = fminf(fmaxf(coeff_act[ND + n], -1.f), 1.f);
      ws[WS_ALPHA + n] = ((c1 + gum_act[ND + n]) > (c0 + gum_act[n])) ? 1.f : 0.f;
    }
    if (t == 0) out[POWER_IDX] = 0.f;
  } else if (b == 1) {
    for (int i = t; i < MM; i += 256) {
      float c0 = fminf(fmaxf(coeff_neg[i], -1.f), 1.f);
      float c1 = fminf(fmaxf(coeff_neg[MM + i], -1.f), 1.f);
      ws[WS_BETA + i] = ((c1 + gum_neg[MM + i]) > (c0 + gum_neg[i])) ? 1.f : 0.f;
    }
  }
}

// ---- k_gt: gt = |tc| * 0.1/colmin ; also per-chunk column sums of gt ----
__global__ __launch_bounds__(256) void k_gt(const float* __restrict__ theta_,
                                            float* __restrict__ ws) {
  int b = blockIdx.x, t = threadIdx.x;
  int n4 = t * 4;
  float g0 = 1e30f, g1 = 1e30f, g2 = 1e30f, g3 = 1e30f;
#pragma unroll 8
  for (int c = 0; c < 32; c++) {
    float4 v = *(const float4*)(ws + WS_GMINP + c * ND + n4);
    g0 = fminf(g0, v.x); g1 = fminf(g1, v.y);
    g2 = fminf(g2, v.z); g3 = fminf(g3, v.w);
  }
  float s0 = 0.1f * frcp(g0), s1 = 0.1f * frcp(g1);
  float s2 = 0.1f * frcp(g2), s3 = 0.1f * frcp(g3);
  int m0 = b * 32, m1 = (b == 31) ? MM : m0 + 32;
  float a0 = 0.f, a1 = 0.f, a2 = 0.f, a3 = 0.f;
  for (int m = m0; m < m1; m++) {
    float4 tv = *(const float4*)(theta_ + m * ND + n4);
    float q0 = fabsf(fminf(fmaxf(tv.x, -1.f), 1.f)) * s0;
    float q1 = fabsf(fminf(fmaxf(tv.y, -1.f), 1.f)) * s1;
    float q2 = fabsf(fminf(fmaxf(tv.z, -1.f), 1.f)) * s2;
    float q3 = fabsf(fminf(fmaxf(tv.w, -1.f), 1.f)) * s3;
    float4 o = {q0, q1, q2, q3};
    *(float4*)(ws + WS_GT + m * ND + n4) = o;
    a0 += q0; a1 += q1; a2 += q2; a3 += q3;
  }
  float4 so = {a0, a1, a2, a3};
  *(float4*)(ws + WS_GSUMP + b * ND + n4) = so;
}

// ---- k_s: per-(fv,chunk) partial sums of |tn| over m ----
__global__ __launch_bounds__(256) void k_s(const float* __restrict__ noise,
                                           const float* __restrict__ fault,
                                           float* __restrict__ ws) {
  int chunk = blockIdx.x, fv = blockIdx.y, f = fv >> 2;
  int t = threadIdx.x, n4 = t * 4;
  int m0 = chunk * 32, m1 = (chunk == 31) ? MM : m0 + 32;
  const float* __restrict__ np_ = noise + (size_t)fv * MM * ND;
  const float* __restrict__ fp = fault + (size_t)f * MM * ND;
  float s0 = 0.f, s1 = 0.f, s2 = 0.f, s3 = 0.f;
#pragma unroll 4
  for (int m = m0; m < m1; m++) {
    float4 tv = *(const float4*)(ws + WS_THETA + m * ND + n4);
    float4 uv = *(const float4*)(np_ + (size_t)m * ND + n4);
    float4 fv4 = *(const float4*)(fp + (size_t)m * ND + n4);
    s0 += fabsf(tv.x * fmaf(uv.x, 0.2f, 0.9f) * fv4.x);
    s1 += fabsf(tv.y * fmaf(uv.y, 0.2f, 0.9f) * fv4.y);
    s2 += fabsf(tv.z * fmaf(uv.z, 0.2f, 0.9f) * fv4.z);
    s3 += fabsf(tv.w * fmaf(uv.w, 0.2f, 0.9f) * fv4.w);
  }
  float4 o = {s0, s1, s2, s3};
  *(float4*)(ws + WS_SP + (size_t)(fv * 32 + chunk) * ND + n4) = o;
}

// ---- fused main ----
#define LOADA(mc)                                                         \
  {                                                                       \
    pa0 = *(const float4*)(aslab + arow0 * NIND + (mc) + acol0);          \
    pa1 = *(const float4*)(aslab + (arow0 + 32) * NIND + (mc) + acol0);   \
  }
#define LOADW1(mc)                                                        \
  {                                                                       \
    _Pragma("unroll") for (int r = 0; r < 4; r++) {                       \
      int idx = ((mc) + wmr * 4 + r) * ND + n0 + wcol;                    \
      pth[r] = theta[idx]; pu[r] = nslab[idx]; pfl[r] = fslab[idx];       \
    }                                                                     \
  }
#define LOADW2(mc)                                                        \
  {                                                                       \
    _Pragma("unroll") for (int r = 0; r < 4; r++) {                       \
      int idx = ((mc) + wmr * 4 + r) * ND + n0 + wcol;                    \
      pth[r] = theta[idx]; pfl[r] = fslab[idx]; pu[r] = gts[idx];         \
    }                                                                     \
  }
#define STOREA(p, mc)                                                     \
  {                                                                       \
    float xs0[4] = {pa0.x, pa0.y, pa0.z, pa0.w};                          \
    float xs1[4] = {pa1.x, pa1.y, pa1.z, pa1.w};                          \
    _Pragma("unroll") for (int ii = 0; ii < 4; ii++) {                    \
      int m = acol0 + ii;                                                 \
      float bs = bets[(mc) + m];                                          \
      float x0 = xs0[ii], x1 = xs1[ii];                                   \
      float v0 = (bs != 0.f) ? frcp(1.f + __expf(fmaf(4.f, x0, -2.f)))    \
                             : (1.f - x0);                                \
      float v1 = (bs != 0.f) ? frcp(1.f + __expf(fmaf(4.f, x1, -2.f)))    \
                             : (1.f - x1);                                \
      axs[p][m][arow0] = x0; ans[p][m][arow0] = v0;                       \
      axs[p][m][arow0 + 32] = x1; ans[p][m][arow0 + 32] = v1;             \
    }                                                                     \
  }
#define BARRIER()                                                         \
  {                                                                       \
    asm volatile("s_waitcnt lgkmcnt(0)" ::: "memory");                    \
    __builtin_amdgcn_s_barrier();                                         \
  }

__global__ __launch_bounds__(256) void k_main(
    const float* __restrict__ a, const float* __restrict__ noise,
    const float* __restrict__ fault, const float* __restrict__ ws,
    float* __restrict__ out) {
  const int tid = threadIdx.x;
  const int tn4 = (tid & 7) * 4;       // 4 n per thread
  const int e0 = (tid >> 3) * 2;       // 2 e per thread
  const int wcol = tid & 31, wmr = tid >> 5;
  const int arow0 = tid >> 3, acol0 = (tid & 7) * 4;
  const int fv = blockIdx.y, f = fv >> 2;
  const int n0 = blockIdx.x * 32, nb = n0 + tn4;

  const float* __restrict__ aslab = a + (size_t)fv * NE * NIND;
  const float* __restrict__ nslab = noise + (size_t)fv * MM * ND;
  const float* __restrict__ fslab = fault + (size_t)f * MM * ND;
  const float* __restrict__ theta = ws + WS_THETA;
  const float* __restrict__ gts = ws + WS_GT;

  __shared__ float axs[2][BK][70];
  __shared__ float ans[2][BK][70];
  __shared__ float wps[2][BK][32];
  __shared__ float wns[2][BK][32];
  __shared__ float bets[1032];
  __shared__ float red[256];

  for (int i = tid; i < MM; i += 256) bets[i] = ws[WS_BETA + i];

  // reduce S partials (32 chunks) and Gsum partials
  float4 sv = {0.f, 0.f, 0.f, 0.f}, gsv = {0.f, 0.f, 0.f, 0.f};
  float sw = 0.f;
#pragma unroll 8
  for (int c = 0; c < 32; c++) {
    float4 x = *(const float4*)(ws + WS_SP + (size_t)(fv * 32 + c) * ND + nb);
    sv.x += x.x; sv.y += x.y; sv.z += x.z; sv.w += x.w;
    float4 y = *(const float4*)(ws + WS_GSUMP + c * ND + nb);
    gsv.x += y.x; gsv.y += y.y; gsv.z += y.z; gsv.w += y.w;
    sw += ws[WS_SP + (size_t)(fv * 32 + c) * ND + n0 + wcol];
  }
  float invs[4] = {frcp(sv.x + 1e-10f), frcp(sv.y + 1e-10f),
                   frcp(sv.z + 1e-10f), frcp(sv.w + 1e-10f)};
  float Gsum[4] = {gsv.x, gsv.y, gsv.z, gsv.w};
  const float ivw = frcp(sw + 1e-10f);
  __syncthreads();

  float4 pa0, pa1;
  float pth[4], pu[4], pfl[4];
  float acc[2][4] = {};

  // ================= phase 1: z =================
  LOADA(0); LOADW1(0);
  for (int mc = 0, p = 0; mc < 1024; mc += BK, p ^= 1) {
    STOREA(p, mc);
#pragma unroll
    for (int r = 0; r < 4; r++) {
      float tw = pth[r] * fmaf(pu[r], 0.2f, 0.9f) * pfl[r];
      float w = fabsf(tw) * ivw;
      float wpv = (tw >= 0.f) ? w : 0.f;
      wps[p][wmr * 4 + r][wcol] = wpv;
      wns[p][wmr * 4 + r][wcol] = w - wpv;
    }
    if (mc + BK < 1024) { LOADA(mc + BK); LOADW1(mc + BK); }
    BARRIER();
#pragma unroll
    for (int j = 0; j < BK; j++) {
      float2 ax2 = *(const float2*)&axs[p][j][e0];
      float2 an2 = *(const float2*)&ans[p][j][e0];
      float4 wp4 = *(const float4*)&wps[p][j][tn4];
      float4 wn4 = *(const float4*)&wns[p][j][tn4];
      float axv[2] = {ax2.x, ax2.y}, anv[2] = {an2.x, an2.y};
      float wpv[4] = {wp4.x, wp4.y, wp4.z, wp4.w};
      float wnv[4] = {wn4.x, wn4.y, wn4.z, wn4.w};
#pragma unroll
      for (int i = 0; i < 2; i++)
#pragma unroll
        for (int k = 0; k < 4; k++)
          acc[i][k] = fmaf(axv[i], wpv[k], fmaf(anv[i], wnv[k], acc[i][k]));
    }
  }
  // tail m=1024 (ax=1, an=anb); m=1025 contributes 0 to z
  const float anb = (bets[1024] != 0.f) ? frcp(1.f + __expf(2.f)) : 0.f;
#pragma unroll
  for (int k = 0; k < 4; k++) {
    int idx = 1024 * ND + nb + k;
    float tw = theta[idx] * fmaf(nslab[idx], 0.2f, 0.9f) * fslab[idx];
    float w = fabsf(tw) * invs[k];
    float wpv = (tw >= 0.f) ? w : 0.f;
    float add = wpv + (w - wpv) * anb;
    acc[0][k] += add; acc[1][k] += add;
  }

  // ================= epilogue: a_new =================
#pragma unroll
  for (int i = 0; i < 2; i++) {
    float4 o;
    float* op = (float*)&o;
#pragma unroll
    for (int k = 0; k < 4; k++) {
      float z = acc[i][k];
      float s0 = frcp(1.f + __expf(fmaf(-4.f, z, 2.f)));
      float t1 = 1.f - 2.f * frcp(__expf(2.f * z) + 1.f);
      op[k] = (ws[WS_ALPHA + nb + k] != 0.f) ? t1 : s0;
    }
    *(float4*)(out + (size_t)(fv * NE + e0 + i) * ND + nb) = o;
  }

  // ================= phase 2: power =================
  float szz[4];
#pragma unroll
  for (int k = 0; k < 4; k++)
    szz[k] = fmaf(acc[1][k], acc[1][k], acc[0][k] * acc[0][k]);
  float GA0[4] = {}, GA1[4] = {}, GB0[4] = {}, GB1[4] = {};
  float SA = 0.f, SB = 0.f;
  LOADA(0); LOADW2(0);
  for (int mc = 0, p = 0; mc < 1024; mc += BK, p ^= 1) {
    STOREA(p, mc);
#pragma unroll
    for (int r = 0; r < 4; r++) {
      bool pp = (pth[r] * pfl[r]) >= 0.f;
      float g = pu[r];
      wps[p][wmr * 4 + r][wcol] = pp ? g : 0.f;
      wns[p][wmr * 4 + r][wcol] = pp ? 0.f : g;
    }
    if (mc + BK < 1024) { LOADA(mc + BK); LOADW2(mc + BK); }
    BARRIER();
#pragma unroll
    for (int j = 0; j < BK; j++) {
      float2 ax2 = *(const float2*)&axs[p][j][e0];
      float2 an2 = *(const float2*)&ans[p][j][e0];
      float4 gp4 = *(const float4*)&wps[p][j][tn4];
      float4 gq4 = *(const float4*)&wns[p][j][tn4];
      float gpv[4] = {gp4.x, gp4.y, gp4.z, gp4.w};
      float gqv[4] = {gq4.x, gq4.y, gq4.z, gq4.w};
      float sa2 = fmaf(ax2.y, ax2.y, ax2.x * ax2.x);
      float sb2 = fmaf(an2.y, an2.y, an2.x * an2.x);
      float gpS = (gpv[0] + gpv[1]) + (gpv[2] + gpv[3]);
      float gqS = (gqv[0] + gqv[1]) + (gqv[2] + gqv[3]);
      SA = fmaf(sa2, gpS, SA);
      SB = fmaf(sb2, gqS, SB);
#pragma unroll
      for (int k = 0; k < 4; k++) {
        GA0[k] = fmaf(ax2.x, gpv[k], GA0[k]);
        GA1[k] = fmaf(ax2.y, gpv[k], GA1[k]);
        GB0[k] = fmaf(an2.x, gqv[k], GB0[k]);
        GB1[k] = fmaf(an2.y, gqv[k], GB1[k]);
      }
    }
  }
  float pacc = SA + SB;
#pragma unroll
  for (int k = 0; k < 4; k++) {
    pacc = fmaf(szz[k], Gsum[k], pacc);  // sum gt*z^2 over ALL m (incl 1024,1025)
    pacc -= 2.f * (acc[0][k] * (GA0[k] + GB0[k]) + acc[1][k] * (GA1[k] + GB1[k]));
  }
  // tail m=1024: sel=1 or anb -> 2*g*sel*(sel - (z0+z1)); z^2 part in Gsum
#pragma unroll
  for (int k = 0; k < 4; k++) {
    int idx = 1024 * ND + nb + k;
    float th = theta[idx], fl = fslab[idx], g = gts[idx];
    float sel = ((th * fl) >= 0.f) ? 1.f : anb;
    float zsum = acc[0][k] + acc[1][k];
    pacc += 2.f * g * sel * (sel - zsum);
  }

  red[tid] = pacc;
  __syncthreads();
  for (int s = 128; s > 0; s >>= 1) {
    if (tid < s) red[tid] += red[tid + s];
    __syncthreads();
  }
  if (tid == 0) atomicAdd(out + POWER_IDX, red[0] * (1.f / 1024.f));
}

extern "C" void kernel_launch(void* const* d_in, const int* in_sizes, int n_in,
                              void* d_out, int out_size, void* d_ws, size_t ws_size,
                              hipStream_t stream) {
  const float* a = (const float*)d_in[0];
  const float* theta_ = (const float*)d_in[1];
  const float* coeff_act = (const float*)d_in[2];
  const float* coeff_neg = (const float*)d_in[3];
  const float* noise_u = (const float*)d_in[4];
  const float* gum_act = (const float*)d_in[5];
  const float* gum_neg = (const float*)d_in[6];
  const float* fault = (const float*)d_in[7];
  float* out = (float*)d_out;
  float* ws = (float*)d_ws;

  k_prep<<<32, 256, 0, stream>>>(theta_, coeff_act, coeff_neg, gum_act, gum_neg, ws, out);
  k_gt<<<32, 256, 0, stream>>>(theta_, ws);
  k_s<<<dim3(32, 16), 256, 0, stream>>>(noise_u, fault, ws);
  k_main<<<dim3(32, 16), 256, 0, stream>>>(a, noise_u, fault, ws, out);
}

// Round 3
// 222.846 us; speedup vs baseline: 3.5034x; 1.7755x over previous
//
#include <hip/hip_runtime.h>

typedef float f32x4 __attribute__((ext_vector_type(4)));
typedef short bf16x8 __attribute__((ext_vector_type(8)));

#define NE 64
#define ND 1024
#define MM 1026

// ws float offsets
#define WS_THETA 0
#define WS_GMINP 1050624
#define WS_GSUMP 1083392
#define WS_SP    1116160
#define WS_ALPHA 1640448
#define WS_BETA  1641472
#define WS_AA    1642504
#define WS_BB    1658888
#define WS_TFG   1675272
#define WS_AXB   5877768
#define WS_ANB   6402056
#define POWER_IDX 1048576

__device__ __forceinline__ float frcp(float x) { return __builtin_amdgcn_rcpf(x); }
__device__ __forceinline__ unsigned f2b(float x) {  // f32 -> bf16 (RNE), in low 16
  unsigned u = __float_as_uint(x);
  u += 0x7FFF + ((u >> 16) & 1);
  return u >> 16;
}
__device__ __forceinline__ float b2f(unsigned b) {  // low16 bf16 -> f32
  return __uint_as_float(b << 16);
}

// ---- k_prep: theta forward value + per-chunk col-min + selectors + power=0 ----
__global__ __launch_bounds__(256) void k_prep(
    const float* __restrict__ theta_, const float* __restrict__ coeff_act,
    const float* __restrict__ coeff_neg, const float* __restrict__ gum_act,
    const float* __restrict__ gum_neg, float* __restrict__ ws,
    float* __restrict__ out) {
  int b = blockIdx.x, t = threadIdx.x;
  int n4 = t * 4;
  int m0 = b * 32, m1 = (b == 31) ? MM : m0 + 32;
  float mn0 = 1e30f, mn1 = 1e30f, mn2 = 1e30f, mn3 = 1e30f;
  for (int m = m0; m < m1; m++) {
    float4 tv = *(const float4*)(theta_ + m * ND + n4);
    float c0 = fminf(fmaxf(tv.x, -1.f), 1.f);
    float c1 = fminf(fmaxf(tv.y, -1.f), 1.f);
    float c2 = fminf(fmaxf(tv.z, -1.f), 1.f);
    float c3 = fminf(fmaxf(tv.w, -1.f), 1.f);
    float g0 = fabsf(c0), g1 = fabsf(c1), g2 = fabsf(c2), g3 = fabsf(c3);
    float4 o = {g0 < 0.01f ? 0.f : c0, g1 < 0.01f ? 0.f : c1,
                g2 < 0.01f ? 0.f : c2, g3 < 0.01f ? 0.f : c3};
    *(float4*)(ws + WS_THETA + m * ND + n4) = o;
    mn0 = fminf(mn0, g0); mn1 = fminf(mn1, g1);
    mn2 = fminf(mn2, g2); mn3 = fminf(mn3, g3);
  }
  float4 mo = {mn0, mn1, mn2, mn3};
  *(float4*)(ws + WS_GMINP + b * ND + n4) = mo;
  if (b == 0) {
#pragma unroll
    for (int k = 0; k < 4; k++) {
      int n = n4 + k;
      float c0 = fminf(fmaxf(coeff_act[n], -1.f), 1.f);
      float c1 = fminf(fmaxf(coeff_act[ND + n], -1.f), 1.f);
      ws[WS_ALPHA + n] = ((c1 + gum_act[ND + n]) > (c0 + gum_act[n])) ? 1.f : 0.f;
    }
    if (t == 0) out[POWER_IDX] = 0.f;
  } else if (b == 1) {
    for (int i = t; i < MM; i += 256) {
      float c0 = fminf(fmaxf(coeff_neg[i], -1.f), 1.f);
      float c1 = fminf(fmaxf(coeff_neg[MM + i], -1.f), 1.f);
      ws[WS_BETA + i] = ((c1 + gum_neg[MM + i]) > (c0 + gum_neg[i])) ? 1.f : 0.f;
    }
  }
}

// ---- k_tf: tfg[f][m][n] = pack(bf16(gt), bf16(theta_fwd*fault)); Gsum partials (f==0)
__global__ __launch_bounds__(256) void k_tf(const float* __restrict__ theta_,
                                            const float* __restrict__ fault,
                                            float* __restrict__ ws) {
  int chunk = blockIdx.x, f = blockIdx.y, t = threadIdx.x;
  int n4 = t * 4;
  float g0 = 1e30f, g1 = 1e30f, g2 = 1e30f, g3 = 1e30f;
#pragma unroll 8
  for (int c = 0; c < 32; c++) {
    float4 v = *(const float4*)(ws + WS_GMINP + c * ND + n4);
    g0 = fminf(g0, v.x); g1 = fminf(g1, v.y);
    g2 = fminf(g2, v.z); g3 = fminf(g3, v.w);
  }
  float s0 = 0.1f * frcp(g0), s1 = 0.1f * frcp(g1);
  float s2 = 0.1f * frcp(g2), s3 = 0.1f * frcp(g3);
  int m0 = chunk * 32, m1 = (chunk == 31) ? MM : m0 + 32;
  unsigned* tfg = (unsigned*)(ws + WS_TFG) + (size_t)f * MM * ND;
  const float* fslab = fault + (size_t)f * MM * ND;
  float a0 = 0.f, a1 = 0.f, a2 = 0.f, a3 = 0.f;
  for (int m = m0; m < m1; m++) {
    float4 tv = *(const float4*)(theta_ + m * ND + n4);
    float4 tw = *(const float4*)(ws + WS_THETA + m * ND + n4);
    float4 fl = *(const float4*)(fslab + (size_t)m * ND + n4);
    float q0 = fabsf(fminf(fmaxf(tv.x, -1.f), 1.f)) * s0;
    float q1 = fabsf(fminf(fmaxf(tv.y, -1.f), 1.f)) * s1;
    float q2 = fabsf(fminf(fmaxf(tv.z, -1.f), 1.f)) * s2;
    float q3 = fabsf(fminf(fmaxf(tv.w, -1.f), 1.f)) * s3;
    uint4 o;
    o.x = (f2b(q0) << 16) | f2b(tw.x * fl.x);
    o.y = (f2b(q1) << 16) | f2b(tw.y * fl.y);
    o.z = (f2b(q2) << 16) | f2b(tw.z * fl.z);
    o.w = (f2b(q3) << 16) | f2b(tw.w * fl.w);
    *(uint4*)(tfg + (size_t)m * ND + n4) = o;
    a0 += q0; a1 += q1; a2 += q2; a3 += q3;
  }
  if (f == 0) {
    float4 so = {a0, a1, a2, a3};
    *(float4*)(ws + WS_GSUMP + chunk * ND + n4) = so;
  }
}

// ---- k_ablob: bf16 A fragments in MFMA lane order + AA/BB (sum_e ax^2, an^2) ----
__global__ __launch_bounds__(256) void k_ablob(const float* __restrict__ a,
                                               float* __restrict__ ws) {
  int kc = blockIdx.x, fv = blockIdx.y, t = threadIdx.x;
  int em = t >> 6, l = t & 63;
  int e = em * 16 + (l & 15);
  int kk = kc * 32 + ((l >> 4) & 3) * 4;
  const float* ap = a + ((size_t)fv * NE + e) * 1024;
  float4 x0 = *(const float4*)(ap + kk);
  float4 x1 = *(const float4*)(ap + kk + 16);
  float xs[8] = {x0.x, x0.y, x0.z, x0.w, x1.x, x1.y, x1.z, x1.w};
  __shared__ float la[256][8];
  __shared__ float lb[256][8];
  unsigned axp[8], anp[8];
#pragma unroll
  for (int j = 0; j < 8; j++) {
    int m = (j < 4) ? (kk + j) : (kk + 12 + j);
    float x = xs[j];
    float bs = ws[WS_BETA + m];
    float an = (bs != 0.f) ? frcp(1.f + __expf(fmaf(4.f, x, -2.f))) : (1.f - x);
    axp[j] = f2b(x);
    anp[j] = f2b(an);
    la[t][j] = x * x;
    lb[t][j] = an * an;
  }
  uint4 ox = {axp[0] | (axp[1] << 16), axp[2] | (axp[3] << 16),
              axp[4] | (axp[5] << 16), axp[6] | (axp[7] << 16)};
  uint4 on = {anp[0] | (anp[1] << 16), anp[2] | (anp[3] << 16),
              anp[4] | (anp[5] << 16), anp[6] | (anp[7] << 16)};
  size_t bidx = ((size_t)(fv * 32 + kc) * 4 + em) * 64 + l;
  ((uint4*)(ws + WS_AXB))[bidx] = ox;
  ((uint4*)(ws + WS_ANB))[bidx] = on;
  __syncthreads();
  if (t < 32) {
    int g = (t >> 2) & 3, j = (t & 3) + 4 * (t >> 4);
    float sa = 0.f, sb = 0.f;
#pragma unroll
    for (int em2 = 0; em2 < 4; em2++)
#pragma unroll
      for (int i = 0; i < 16; i++) {
        sa += la[em2 * 64 + g * 16 + i][j];
        sb += lb[em2 * 64 + g * 16 + i][j];
      }
    ws[WS_AA + fv * 1024 + kc * 32 + t] = sa;
    ws[WS_BB + fv * 1024 + kc * 32 + t] = sb;
  }
}

// ---- k_s: S[fv][n] partial sums of |t| over m-chunks ----
__global__ __launch_bounds__(256) void k_s(const float* __restrict__ noise,
                                           float* __restrict__ ws) {
  int chunk = blockIdx.x, fv = blockIdx.y, f = fv >> 2;
  int t = threadIdx.x, n4 = t * 4;
  int m0 = chunk * 32, m1 = (chunk == 31) ? MM : m0 + 32;
  const unsigned* tslab = (const unsigned*)(ws + WS_TFG) + (size_t)f * MM * ND;
  const float* nslab = noise + (size_t)fv * MM * ND;
  float s0 = 0.f, s1 = 0.f, s2 = 0.f, s3 = 0.f;
  for (int m = m0; m < m1; m++) {
    uint4 tg = *(const uint4*)(tslab + (size_t)m * ND + n4);
    float4 uv = *(const float4*)(nslab + (size_t)m * ND + n4);
    s0 += b2f(tg.x & 0x7FFF) * fmaf(uv.x, 0.2f, 0.9f);
    s1 += b2f(tg.y & 0x7FFF) * fmaf(uv.y, 0.2f, 0.9f);
    s2 += b2f(tg.z & 0x7FFF) * fmaf(uv.z, 0.2f, 0.9f);
    s3 += b2f(tg.w & 0x7FFF) * fmaf(uv.w, 0.2f, 0.9f);
  }
  float4 o = {s0, s1, s2, s3};
  *(float4*)(ws + WS_SP + (size_t)(fv * 32 + chunk) * ND + n4) = o;
}

// ---- fused main: MFMA z & G, activation, power ----
union U8 { uint4 u; bf16x8 h; };

#define SLOAD(MC)                                                          \
  {                                                                        \
    _Pragma("unroll") for (int r = 0; r < 8; r++) {                        \
      size_t row = (size_t)((MC) + mb + r) * ND;                           \
      uA[r] = nslab[row + n0 + nin];                                       \
      uB[r] = nslab[row + n0 + 16 + nin];                                  \
      tgA[r] = tslab[row + n0 + nin];                                      \
      tgB[r] = tslab[row + n0 + 16 + nin];                                 \
    }                                                                      \
    aa0 = *(const float4*)(AAp + (MC) + mb);                               \
    aa1 = *(const float4*)(AAp + (MC) + mb + 4);                           \
    bb0 = *(const float4*)(BBp + (MC) + mb);                               \
    bb1 = *(const float4*)(BBp + (MC) + mb + 4);                           \
  }

#define SWRITE(P)                                                          \
  {                                                                        \
    float aas[8] = {aa0.x, aa0.y, aa0.z, aa0.w, aa1.x, aa1.y, aa1.z, aa1.w};\
    float bbs[8] = {bb0.x, bb0.y, bb0.z, bb0.w, bb1.x, bb1.y, bb1.z, bb1.w};\
    unsigned wpu[2][8], wnu[2][8], gpu[2][8], gqu[2][8];                   \
    _Pragma("unroll") for (int h = 0; h < 2; h++) {                        \
      float ivw = h ? ivwb : ivwa;                                         \
      _Pragma("unroll") for (int r = 0; r < 8; r++) {                      \
        unsigned tg = h ? tgB[r] : tgA[r];                                 \
        float u = h ? uB[r] : uA[r];                                       \
        unsigned neg = (tg >> 15) & 1;                                     \
        float aw = b2f(tg & 0x7FFF) * fmaf(u, 0.2f, 0.9f) * ivw;           \
        unsigned wb = f2b(aw);                                             \
        unsigned gb = tg >> 16;                                            \
        wpu[h][r] = neg ? 0u : wb;  wnu[h][r] = neg ? wb : 0u;             \
        gpu[h][r] = neg ? 0u : gb;  gqu[h][r] = neg ? gb : 0u;             \
        float gtf = __uint_as_float(tg & 0xFFFF0000u);                     \
        pacc = fmaf(gtf, neg ? bbs[r] : aas[r], pacc);                     \
      }                                                                    \
    }                                                                      \
    _Pragma("unroll") for (int pn = 0; pn < 4; pn++) {                     \
      uint2* pp = (uint2*)&panels[P][pn][0];                               \
      _Pragma("unroll") for (int h = 0; h < 2; h++) {                      \
        const unsigned* v = pn == 0 ? wpu[h] : pn == 1 ? wnu[h]            \
                             : pn == 2 ? gpu[h] : gqu[h];                  \
        int s0i = ((c_s * 2 + h) * 64 + (g0 & 3) * 16 + nin) * 2 + j0q;    \
        int s1i = ((c_s * 2 + h) * 64 + ((g0 + 1) & 3) * 16 + nin) * 2 + j0q;\
        pp[s0i] = make_uint2(v[0] | (v[1] << 16), v[2] | (v[3] << 16));    \
        pp[s1i] = make_uint2(v[4] | (v[5] << 16), v[6] | (v[7] << 16));    \
      }                                                                    \
    }                                                                      \
  }

#define ALOAD(KS)                                                          \
  {                                                                        \
    _Pragma("unroll") for (int c = 0; c < 2; c++)                          \
      _Pragma("unroll") for (int mi = 0; mi < 4; mi++) {                   \
        size_t bi = ((size_t)(fv * 32 + (KS) * 2 + c) * 4 + mi) * 64 + l;  \
        axr[c][mi] = axbp[bi];                                             \
        anr[c][mi] = anbp[bi];                                             \
      }                                                                    \
  }

#define BMFMA(P)                                                           \
  {                                                                        \
    _Pragma("unroll") for (int c = 0; c < 2; c++) {                        \
      int bslot = (c * 2 + w) * 64 + l;                                    \
      U8 bwp, bwn, bgp, bgq;                                               \
      bwp.u = panels[P][0][bslot]; bwn.u = panels[P][1][bslot];            \
      bgp.u = panels[P][2][bslot]; bgq.u = panels[P][3][bslot];            \
      _Pragma("unroll") for (int mi = 0; mi < 4; mi++) {                   \
        U8 ax, an; ax.u = axr[c][mi]; an.u = anr[c][mi];                   \
        accz[mi] = __builtin_amdgcn_mfma_f32_16x16x32_bf16(ax.h, bwp.h, accz[mi], 0, 0, 0); \
        accz[mi] = __builtin_amdgcn_mfma_f32_16x16x32_bf16(an.h, bwn.h, accz[mi], 0, 0, 0); \
        accg[mi] = __builtin_amdgcn_mfma_f32_16x16x32_bf16(ax.h, bgp.h, accg[mi], 0, 0, 0); \
        accg[mi] = __builtin_amdgcn_mfma_f32_16x16x32_bf16(an.h, bgq.h, accg[mi], 0, 0, 0); \
      }                                                                    \
    }                                                                      \
  }

__global__ __launch_bounds__(128) void k_main(
    const float* __restrict__ noise, const float* __restrict__ ws_c,
    float* __restrict__ ws, float* __restrict__ out) {
  const int tid = threadIdx.x;
  const int w = tid >> 6, l = tid & 63;
  const int fv = blockIdx.y, f = fv >> 2;
  const int n0 = blockIdx.x * 32;

  __shared__ uint4 panels[2][4][256];
  __shared__ float invs_l[32], gsum_l[32], alpha_l[32];
  __shared__ float red[128];

  if (tid < 32) {
    float s = 0.f;
#pragma unroll 8
    for (int c = 0; c < 32; c++) s += ws_c[WS_SP + (size_t)(fv * 32 + c) * ND + n0 + tid];
    invs_l[tid] = frcp(s + 1e-10f);
  } else if (tid < 64) {
    int n = tid - 32; float s = 0.f;
#pragma unroll 8
    for (int c = 0; c < 32; c++) s += ws_c[WS_GSUMP + c * ND + n0 + n];
    gsum_l[n] = s;
  } else if (tid < 96) {
    alpha_l[tid - 64] = ws_c[WS_ALPHA + n0 + tid - 64];
  }

  const int nin = tid & 15;
  const int mb = (tid >> 4) * 8;
  const int c_s = mb >> 5;
  const int g0 = (mb & 31) >> 2;
  const int j0q = (mb & 31) >> 4;
  const unsigned* tslab = (const unsigned*)(ws_c + WS_TFG) + (size_t)f * MM * ND;
  const float* nslab = noise + (size_t)fv * MM * ND;
  const float* AAp = ws_c + WS_AA + fv * 1024;
  const float* BBp = ws_c + WS_BB + fv * 1024;
  const uint4* axbp = (const uint4*)(ws_c + WS_AXB);
  const uint4* anbp = (const uint4*)(ws_c + WS_ANB);

  float pacc = 0.f;
  float uA[8], uB[8];
  unsigned tgA[8], tgB[8];
  float4 aa0, aa1, bb0, bb1;
  uint4 axr[2][4], anr[2][4];
  f32x4 accz[4] = {};
  f32x4 accg[4] = {};

  __syncthreads();
  const float ivwa = invs_l[nin], ivwb = invs_l[16 + nin];

  SLOAD(0);
  SWRITE(0);
  __syncthreads();
  for (int ks = 0; ks < 16; ks++) {
    int p = ks & 1;
    if (ks < 15) { SLOAD((ks + 1) * 64); }
    ALOAD(ks);
    if (ks < 15) { SWRITE(p ^ 1); }
    BMFMA(p);
    __syncthreads();
  }

  // ---- epilogue ----
  const int n_loc = w * 16 + (l & 15);
  const int n_e = n0 + n_loc;
  const float anb = (ws_c[WS_BETA + 1024] != 0.f) ? frcp(1.f + __expf(2.f)) : 0.f;
  unsigned tg24 = tslab[(size_t)1024 * ND + n_e];
  float u24 = nslab[(size_t)1024 * ND + n_e];
  unsigned neg24 = (tg24 >> 15) & 1;
  float w24 = b2f(tg24 & 0x7FFF) * fmaf(u24, 0.2f, 0.9f) * invs_l[n_loc];
  float ztail = neg24 ? w24 * anb : w24;
  float gt24 = __uint_as_float(tg24 & 0xFFFF0000u);
  float tailG = neg24 ? anb * gt24 : gt24;
  if (l < 16) pacc += neg24 ? 64.f * anb * anb * gt24 : 64.f * gt24;
  const float gsn = gsum_l[n_loc], alv = alpha_l[n_loc];
  float zsum = 0.f;
#pragma unroll
  for (int mi = 0; mi < 4; mi++) {
#pragma unroll
    for (int r = 0; r < 4; r++) {
      float z = accz[mi][r] + ztail;
      zsum += z;
      pacc += gsn * z * z - 2.f * z * accg[mi][r];
      float s0 = frcp(1.f + __expf(fmaf(-4.f, z, 2.f)));
      float t1 = 1.f - 2.f * frcp(__expf(2.f * z) + 1.f);
      int e = mi * 16 + ((l >> 4) & 3) * 4 + r;
      out[((size_t)(fv * NE + e)) * ND + n_e] = (alv != 0.f) ? t1 : s0;
    }
  }
  pacc -= 2.f * zsum * tailG;

  red[tid] = pacc;
  __syncthreads();
  for (int s = 64; s > 0; s >>= 1) {
    if (tid < s) red[tid] += red[tid + s];
    __syncthreads();
  }
  if (tid == 0) atomicAdd(out + POWER_IDX, red[0] * (1.f / 1024.f));
}

extern "C" void kernel_launch(void* const* d_in, const int* in_sizes, int n_in,
                              void* d_out, int out_size, void* d_ws, size_t ws_size,
                              hipStream_t stream) {
  const float* a = (const float*)d_in[0];
  const float* theta_ = (const float*)d_in[1];
  const float* coeff_act = (const float*)d_in[2];
  const float* coeff_neg = (const float*)d_in[3];
  const float* noise_u = (const float*)d_in[4];
  const float* gum_act = (const float*)d_in[5];
  const float* gum_neg = (const float*)d_in[6];
  const float* fault = (const float*)d_in[7];
  float* out = (float*)d_out;
  float* ws = (float*)d_ws;

  k_prep<<<32, 256, 0, stream>>>(theta_, coeff_act, coeff_neg, gum_act, gum_neg, ws, out);
  k_tf<<<dim3(32, 4), 256, 0, stream>>>(theta_, fault, ws);
  k_ablob<<<dim3(32, 16), 256, 0, stream>>>(a, ws);
  k_s<<<dim3(32, 16), 256, 0, stream>>>(noise_u, ws);
  k_main<<<dim3(32, 16), 128, 0, stream>>>(noise_u, ws, ws, out);
}

// Round 6
// 195.508 us; speedup vs baseline: 3.9932x; 1.1398x over previous
//
#include <hip/hip_runtime.h>

typedef float f32x4 __attribute__((ext_vector_type(4)));
typedef short bf16x8 __attribute__((ext_vector_type(8)));

#define NE 64
#define ND 1024
#define MM 1026

// ws float offsets (layout kept from R3; WS_THETA region now unused)
#define WS_GMINP 1050624
#define WS_GSUMP 1083392
#define WS_AA    1642504
#define WS_BB    1658888
#define WS_TFG   1675272
#define WS_AXB   5877768
#define WS_ANB   6402056
#define POWER_IDX 1048576

__device__ __forceinline__ float frcp(float x) { return __builtin_amdgcn_rcpf(x); }
__device__ __forceinline__ unsigned f2b(float x) {  // f32 -> bf16 (RNE), low 16
  unsigned u = __float_as_uint(x);
  u += 0x7FFF + ((u >> 16) & 1);
  return u >> 16;
}
__device__ __forceinline__ float b2f(unsigned b) { return __uint_as_float(b << 16); }
__device__ __forceinline__ float clamp1(float x) { return fminf(fmaxf(x, -1.f), 1.f); }

// ---- k_min: per-m-chunk column minima of |clamp(theta_)|; zero power ----
__global__ __launch_bounds__(256) void k_min(const float* __restrict__ theta_,
                                             float* __restrict__ ws,
                                             float* __restrict__ out) {
  int b = blockIdx.x, t = threadIdx.x;
  int n4 = t * 4;
  int m0 = b * 32, m1 = (b == 31) ? MM : m0 + 32;
  float mn0 = 1e30f, mn1 = 1e30f, mn2 = 1e30f, mn3 = 1e30f;
  for (int m = m0; m < m1; m++) {
    float4 tv = *(const float4*)(theta_ + m * ND + n4);
    mn0 = fminf(mn0, fabsf(clamp1(tv.x)));
    mn1 = fminf(mn1, fabsf(clamp1(tv.y)));
    mn2 = fminf(mn2, fabsf(clamp1(tv.z)));
    mn3 = fminf(mn3, fabsf(clamp1(tv.w)));
  }
  float4 mo = {mn0, mn1, mn2, mn3};
  *(float4*)(ws + WS_GMINP + b * ND + n4) = mo;
  if (b == 0 && t == 0) out[POWER_IDX] = 0.f;
}

// ---- k_pre: 512 ablob-role blocks + 128 tf-role blocks ----
__global__ __launch_bounds__(256) void k_pre(
    const float* __restrict__ a, const float* __restrict__ theta_,
    const float* __restrict__ fault, const float* __restrict__ coeff_neg,
    const float* __restrict__ gum_neg, float* __restrict__ ws) {
  int bid = blockIdx.x, t = threadIdx.x;
  __shared__ float la[256][8];
  __shared__ float lb[256][8];
  __shared__ float beta_l[32];

  if (bid < 512) {
    // ======= ablob role: bf16 A-frags in MFMA order + AA/BB =======
    int kc = bid & 31, fv = bid >> 5;
    if (t < 32) {
      int m = kc * 32 + t;
      float c0 = clamp1(coeff_neg[m]);
      float c1 = clamp1(coeff_neg[MM + m]);
      beta_l[t] = ((c1 + gum_neg[MM + m]) > (c0 + gum_neg[m])) ? 1.f : 0.f;
    }
    __syncthreads();
    int em = t >> 6, l = t & 63;
    int e = em * 16 + (l & 15);
    int g = (l >> 4) & 3;
    int kk = kc * 32 + g * 4;
    const float* ap = a + ((size_t)fv * NE + e) * 1024;
    float4 x0 = *(const float4*)(ap + kk);
    float4 x1 = *(const float4*)(ap + kk + 16);
    float xs[8] = {x0.x, x0.y, x0.z, x0.w, x1.x, x1.y, x1.z, x1.w};
    unsigned axp[8], anp[8];
#pragma unroll
    for (int j = 0; j < 8; j++) {
      int mloc = g * 4 + ((j < 4) ? j : 12 + j);
      float x = xs[j];
      float bs = beta_l[mloc];
      float an = (bs != 0.f) ? frcp(1.f + __expf(fmaf(4.f, x, -2.f))) : (1.f - x);
      axp[j] = f2b(x);
      anp[j] = f2b(an);
      la[t][j] = x * x;
      lb[t][j] = an * an;
    }
    uint4 ox = {axp[0] | (axp[1] << 16), axp[2] | (axp[3] << 16),
                axp[4] | (axp[5] << 16), axp[6] | (axp[7] << 16)};
    uint4 on = {anp[0] | (anp[1] << 16), anp[2] | (anp[3] << 16),
                anp[4] | (anp[5] << 16), anp[6] | (anp[7] << 16)};
    size_t bidx = ((size_t)(fv * 32 + kc) * 4 + em) * 64 + l;
    ((uint4*)(ws + WS_AXB))[bidx] = ox;
    ((uint4*)(ws + WS_ANB))[bidx] = on;
    __syncthreads();
    if (t < 32) {
      int g2 = (t >> 2) & 3, j2 = (t & 3) + 4 * (t >> 4);
      float sa = 0.f, sb = 0.f;
#pragma unroll
      for (int em2 = 0; em2 < 4; em2++)
#pragma unroll
        for (int i = 0; i < 16; i++) {
          sa += la[em2 * 64 + g2 * 16 + i][j2];
          sb += lb[em2 * 64 + g2 * 16 + i][j2];
        }
      ws[WS_AA + fv * 1024 + kc * 32 + t] = sa;
      ws[WS_BB + fv * 1024 + kc * 32 + t] = sb;
    }
  } else {
    // ======= tf role: pack tfg = (bf16(gt)<<16)|bf16(theta_fwd*fault) =======
    int r = bid - 512;
    int f = r >> 5, chunk = r & 31;
    int n4 = t * 4;
    float g0 = 1e30f, g1 = 1e30f, g2 = 1e30f, g3 = 1e30f;
#pragma unroll 8
    for (int c = 0; c < 32; c++) {
      float4 v = *(const float4*)(ws + WS_GMINP + c * ND + n4);
      g0 = fminf(g0, v.x); g1 = fminf(g1, v.y);
      g2 = fminf(g2, v.z); g3 = fminf(g3, v.w);
    }
    float s0 = 0.1f * frcp(g0), s1 = 0.1f * frcp(g1);
    float s2 = 0.1f * frcp(g2), s3 = 0.1f * frcp(g3);
    int m0 = chunk * 32, m1 = (chunk == 31) ? MM : m0 + 32;
    unsigned* tfg = (unsigned*)(ws + WS_TFG) + (size_t)f * MM * ND;
    const float* fslab = fault + (size_t)f * MM * ND;
    float a0 = 0.f, a1 = 0.f, a2 = 0.f, a3 = 0.f;
    for (int m = m0; m < m1; m++) {
      float4 tv = *(const float4*)(theta_ + m * ND + n4);
      float4 fl = *(const float4*)(fslab + (size_t)m * ND + n4);
      float c0 = clamp1(tv.x), c1 = clamp1(tv.y), c2 = clamp1(tv.z), c3 = clamp1(tv.w);
      float z0 = fabsf(c0), z1 = fabsf(c1), z2 = fabsf(c2), z3 = fabsf(c3);
      float q0 = z0 * s0, q1 = z1 * s1, q2 = z2 * s2, q3 = z3 * s3;
      float w0 = (z0 < 0.01f ? 0.f : c0) * fl.x;
      float w1 = (z1 < 0.01f ? 0.f : c1) * fl.y;
      float w2 = (z2 < 0.01f ? 0.f : c2) * fl.z;
      float w3 = (z3 < 0.01f ? 0.f : c3) * fl.w;
      uint4 o;
      o.x = (f2b(q0) << 16) | f2b(w0);
      o.y = (f2b(q1) << 16) | f2b(w1);
      o.z = (f2b(q2) << 16) | f2b(w2);
      o.w = (f2b(q3) << 16) | f2b(w3);
      *(uint4*)(tfg + (size_t)m * ND + n4) = o;
      a0 += q0; a1 += q1; a2 += q2; a3 += q3;
    }
    if (f == 0) {
      float4 so = {a0, a1, a2, a3};
      *(float4*)(ws + WS_GSUMP + chunk * ND + n4) = so;
    }
  }
}

// ---- fused main: MFMA z & G, inline S, activation, power ----
union U8 { uint4 u; bf16x8 h; };

#define SLOAD(S, MC)                                                       \
  {                                                                        \
    _Pragma("unroll") for (int r = 0; r < 8; r++) {                        \
      size_t row = (size_t)((MC) + mb + r) * ND;                           \
      uA##S[r] = nslab[row + n0 + nin];                                    \
      uB##S[r] = nslab[row + n0 + 16 + nin];                               \
      tgA##S[r] = tslab[row + n0 + nin];                                   \
      tgB##S[r] = tslab[row + n0 + 16 + nin];                              \
    }                                                                      \
  }

#define AABBLOAD(MC)                                                       \
  {                                                                        \
    aa0 = *(const float4*)(AAp + (MC) + mb);                               \
    aa1 = *(const float4*)(AAp + (MC) + mb + 4);                           \
    bb0 = *(const float4*)(BBp + (MC) + mb);                               \
    bb1 = *(const float4*)(BBp + (MC) + mb + 4);                           \
  }

#define SWRITE(P, S)                                                       \
  {                                                                        \
    float aas[8] = {aa0.x, aa0.y, aa0.z, aa0.w, aa1.x, aa1.y, aa1.z, aa1.w};\
    float bbs[8] = {bb0.x, bb0.y, bb0.z, bb0.w, bb1.x, bb1.y, bb1.z, bb1.w};\
    unsigned wpu[2][8], wnu[2][8], gpu[2][8], gqu[2][8];                   \
    _Pragma("unroll") for (int h = 0; h < 2; h++) {                        \
      _Pragma("unroll") for (int r = 0; r < 8; r++) {                      \
        unsigned tg = h ? tgB##S[r] : tgA##S[r];                           \
        float u = h ? uB##S[r] : uA##S[r];                                 \
        unsigned neg = (tg >> 15) & 1;                                     \
        float aw = b2f(tg & 0x7FFF) * fmaf(u, 0.2f, 0.9f);                 \
        if (h) sacc1 += aw; else sacc0 += aw;                              \
        unsigned wb = f2b(aw);                                             \
        unsigned gb = tg >> 16;                                            \
        wpu[h][r] = neg ? 0u : wb;  wnu[h][r] = neg ? wb : 0u;             \
        gpu[h][r] = neg ? 0u : gb;  gqu[h][r] = neg ? gb : 0u;             \
        float gtf = __uint_as_float(tg & 0xFFFF0000u);                     \
        pacc = fmaf(gtf, neg ? bbs[r] : aas[r], pacc);                     \
      }                                                                    \
    }                                                                      \
    _Pragma("unroll") for (int pn = 0; pn < 4; pn++) {                     \
      uint2* pp = (uint2*)&panels[P][pn][0];                               \
      _Pragma("unroll") for (int h = 0; h < 2; h++) {                      \
        const unsigned* v = pn == 0 ? wpu[h] : pn == 1 ? wnu[h]            \
                             : pn == 2 ? gpu[h] : gqu[h];                  \
        int s0i = ((c_s * 2 + h) * 64 + (g0 & 3) * 16 + nin) * 2 + j0q;    \
        int s1i = ((c_s * 2 + h) * 64 + ((g0 + 1) & 3) * 16 + nin) * 2 + j0q;\
        pp[s0i] = make_uint2(v[0] | (v[1] << 16), v[2] | (v[3] << 16));    \
        pp[s1i] = make_uint2(v[4] | (v[5] << 16), v[6] | (v[7] << 16));    \
      }                                                                    \
    }                                                                      \
  }

#define ALOAD(KS)                                                          \
  {                                                                        \
    _Pragma("unroll") for (int c = 0; c < 2; c++)                          \
      _Pragma("unroll") for (int mi = 0; mi < 4; mi++) {                   \
        size_t bi = ((size_t)(fv * 32 + (KS) * 2 + c) * 4 + mi) * 64 + l;  \
        axr[c][mi] = axbp[bi];                                             \
        anr[c][mi] = anbp[bi];                                             \
      }                                                                    \
  }

#define BMFMA(P)                                                           \
  {                                                                        \
    _Pragma("unroll") for (int c = 0; c < 2; c++) {                        \
      int bslot = (c * 2 + w) * 64 + l;                                    \
      U8 bwp, bwn, bgp, bgq;                                               \
      bwp.u = panels[P][0][bslot]; bwn.u = panels[P][1][bslot];            \
      bgp.u = panels[P][2][bslot]; bgq.u = panels[P][3][bslot];            \
      _Pragma("unroll") for (int mi = 0; mi < 4; mi++) {                   \
        U8 ax, an; ax.u = axr[c][mi]; an.u = anr[c][mi];                   \
        accz[mi] = __builtin_amdgcn_mfma_f32_16x16x32_bf16(ax.h, bwp.h, accz[mi], 0, 0, 0); \
        accz[mi] = __builtin_amdgcn_mfma_f32_16x16x32_bf16(an.h, bwn.h, accz[mi], 0, 0, 0); \
        accg[mi] = __builtin_amdgcn_mfma_f32_16x16x32_bf16(ax.h, bgp.h, accg[mi], 0, 0, 0); \
        accg[mi] = __builtin_amdgcn_mfma_f32_16x16x32_bf16(an.h, bgq.h, accg[mi], 0, 0, 0); \
      }                                                                    \
    }                                                                      \
  }

#define BAR() __syncthreads()

__global__ __launch_bounds__(128) void k_main(
    const float* __restrict__ noise, const float* __restrict__ ws_c,
    const float* __restrict__ coeff_act, const float* __restrict__ gum_act,
    const float* __restrict__ coeff_neg, const float* __restrict__ gum_neg,
    float* __restrict__ out) {
  const int tid = threadIdx.x;
  const int w = tid >> 6, l = tid & 63;
  const int fv = blockIdx.y, f = fv >> 2;
  const int n0 = blockIdx.x * 32;

  __shared__ uint4 panels[2][4][256];
  __shared__ float gsum_l[32];

  if (tid < 32) {
    float s = 0.f;
#pragma unroll 8
    for (int c = 0; c < 32; c++) s += ws_c[WS_GSUMP + c * ND + n0 + tid];
    gsum_l[tid] = s;
  }

  const int nin = tid & 15;
  const int mb = (tid >> 4) * 8;
  const int c_s = mb >> 5;
  const int g0 = (mb & 31) >> 2;
  const int j0q = (mb & 31) >> 4;
  const unsigned* tslab = (const unsigned*)(ws_c + WS_TFG) + (size_t)f * MM * ND;
  const float* nslab = noise + (size_t)fv * MM * ND;
  const float* AAp = ws_c + WS_AA + fv * 1024;
  const float* BBp = ws_c + WS_BB + fv * 1024;
  const uint4* axbp = (const uint4*)(ws_c + WS_AXB);
  const uint4* anbp = (const uint4*)(ws_c + WS_ANB);

  float pacc = 0.f, sacc0 = 0.f, sacc1 = 0.f;
  float uA0[8], uB0[8], uA1[8], uB1[8];
  unsigned tgA0[8], tgB0[8], tgA1[8], tgB1[8];
  float4 aa0, aa1, bb0, bb1;
  uint4 axr[2][4], anr[2][4];
  f32x4 accz[4] = {};
  f32x4 accg[4] = {};

  // prologue
  AABBLOAD(0);
  SLOAD(0, 0);
  SWRITE(0, 0);          // panel0 <- mc 0
  SLOAD(1, 64);          // set1 <- mc 1
  BAR();

  for (int ks2 = 0; ks2 < 16; ks2 += 2) {
    // ---- body A: ks = ks2 (even), compute panel0, write panel1 ----
    ALOAD(ks2);
    AABBLOAD((ks2 + 1) * 64);
    if (ks2 < 14) SLOAD(0, (ks2 + 2) * 64);
    SWRITE(1, 1);        // panel1 <- mc ks2+1 (regs loaded one iter ago)
    BMFMA(0);            // consume panel0 (mc ks2)
    BAR();
    // ---- body B: ks = ks2+1 (odd), compute panel1, write panel0 ----
    ALOAD(ks2 + 1);
    if (ks2 < 14) {
      AABBLOAD((ks2 + 2) * 64);
      SLOAD(1, (ks2 + 3) * 64);
      SWRITE(0, 0);      // panel0 <- mc ks2+2
    }
    BMFMA(1);            // consume panel1 (mc ks2+1)
    BAR();
  }

  // ---- epilogue: S reduce, tails, activation, power ----
  float* lds_f = (float*)&panels[0][0][0];
  lds_f[(tid >> 4) * 32 + nin] = sacc0;
  lds_f[(tid >> 4) * 32 + 16 + nin] = sacc1;
  __syncthreads();

  const int n_loc = w * 16 + (l & 15);
  const int n_e = n0 + n_loc;
  float S = 0.f;
#pragma unroll
  for (int mg = 0; mg < 8; mg++) S += lds_f[mg * 32 + n_loc];

  unsigned tg24 = tslab[(size_t)1024 * ND + n_e];
  unsigned tg25 = tslab[(size_t)1025 * ND + n_e];
  float u24 = nslab[(size_t)1024 * ND + n_e];
  float u25 = nslab[(size_t)1025 * ND + n_e];
  float w24 = b2f(tg24 & 0x7FFF) * fmaf(u24, 0.2f, 0.9f);
  float w25 = b2f(tg25 & 0x7FFF) * fmaf(u25, 0.2f, 0.9f);
  S += w24 + w25;
  const float invS = frcp(S + 1e-10f);

  float cn0 = clamp1(coeff_neg[1024]), cn1 = clamp1(coeff_neg[MM + 1024]);
  const float anb = ((cn1 + gum_neg[MM + 1024]) > (cn0 + gum_neg[1024]))
                        ? frcp(1.f + __expf(2.f)) : 0.f;
  float ca0 = clamp1(coeff_act[n_e]), ca1 = clamp1(coeff_act[ND + n_e]);
  const float alv = ((ca1 + gum_act[ND + n_e]) > (ca0 + gum_act[n_e])) ? 1.f : 0.f;

  unsigned neg24 = (tg24 >> 15) & 1;
  float sel24 = neg24 ? anb : 1.f;
  float ztail = w24 * invS * sel24;
  float gt24 = __uint_as_float(tg24 & 0xFFFF0000u);
  if (l < 16) pacc += 64.f * gt24 * sel24 * sel24;  // Term1 m=1024 (once per n)

  const float gsn = gsum_l[n_loc];
  float zsum = 0.f;
#pragma unroll
  for (int mi = 0; mi < 4; mi++) {
#pragma unroll
    for (int r = 0; r < 4; r++) {
      float z = accz[mi][r] * invS + ztail;
      zsum += z;
      pacc += gsn * z * z - 2.f * z * accg[mi][r];
      float s0v = frcp(1.f + __expf(fmaf(-4.f, z, 2.f)));
      float t1v = 1.f - 2.f * frcp(__expf(2.f * z) + 1.f);
      int e = mi * 16 + ((l >> 4) & 3) * 4 + r;
      out[((size_t)(fv * NE + e)) * ND + n_e] = (alv != 0.f) ? t1v : s0v;
    }
  }
  pacc -= 2.f * zsum * (gt24 * sel24);  // cross-term m=1024

  float* red = lds_f + 256;
  red[tid] = pacc;
  __syncthreads();
  for (int s = 64; s > 0; s >>= 1) {
    if (tid < s) red[tid] += red[tid + s];
    __syncthreads();
  }
  if (tid == 0) atomicAdd(out + POWER_IDX, red[0] * (1.f / 1024.f));
}

extern "C" void kernel_launch(void* const* d_in, const int* in_sizes, int n_in,
                              void* d_out, int out_size, void* d_ws, size_t ws_size,
                              hipStream_t stream) {
  const float* a = (const float*)d_in[0];
  const float* theta_ = (const float*)d_in[1];
  const float* coeff_act = (const float*)d_in[2];
  const float* coeff_neg = (const float*)d_in[3];
  const float* noise_u = (const float*)d_in[4];
  const float* gum_act = (const float*)d_in[5];
  const float* gum_neg = (const float*)d_in[6];
  const float* fault = (const float*)d_in[7];
  float* out = (float*)d_out;
  float* ws = (float*)d_ws;

  k_min<<<32, 256, 0, stream>>>(theta_, ws, out);
  k_pre<<<640, 256, 0, stream>>>(a, theta_, fault, coeff_neg, gum_neg, ws);
  k_main<<<dim3(32, 16), 128, 0, stream>>>(noise_u, ws, coeff_act, gum_act,
                                           coeff_neg, gum_neg, out);
}

// Round 7
// 174.327 us; speedup vs baseline: 4.4784x; 1.1215x over previous
//
#include <hip/hip_runtime.h>

typedef float f32x4 __attribute__((ext_vector_type(4)));
typedef short bf16x8 __attribute__((ext_vector_type(8)));

#define NE 64
#define ND 1024
#define MM 1026

// ws float offsets
#define WS_GMINP 1050624
#define WS_GABSP 1083392
#define WS_AA    1642504
#define WS_BB    1658888
#define WS_TFG   1675272
#define WS_AXB   5877768
#define WS_ANB   6402056
#define POWER_IDX 1048576

__device__ __forceinline__ float frcp(float x) { return __builtin_amdgcn_rcpf(x); }
__device__ __forceinline__ unsigned f2b(float x) {  // f32 -> bf16 (RNE), low 16
  unsigned u = __float_as_uint(x);
  u += 0x7FFF + ((u >> 16) & 1);
  return u >> 16;
}
__device__ __forceinline__ float b2f(unsigned b) { return __uint_as_float(b << 16); }
__device__ __forceinline__ float clamp1(float x) { return fminf(fmaxf(x, -1.f), 1.f); }

// ---- k_pre: 512 tf-role + 512 ablob-role + 128 min-role blocks (independent) ----
__global__ __launch_bounds__(256) void k_pre(
    const float* __restrict__ a, const float* __restrict__ theta_,
    const float* __restrict__ fault, const float* __restrict__ coeff_neg,
    const float* __restrict__ gum_neg, float* __restrict__ ws,
    float* __restrict__ out) {
  int bid = blockIdx.x, t = threadIdx.x;
  __shared__ float la[256][8];
  __shared__ float lb[256][8];
  __shared__ float beta_l[32];

  if (bid < 512) {
    // ======= tf role: tfg = (bf16(|tc|)<<16) | bf16(tc_zeroed*fault) =======
    int f = bid >> 7, chunk = bid & 127;
    int m0 = chunk * 8, m1 = (chunk == 127) ? MM : m0 + 8;
    unsigned* tfg = (unsigned*)(ws + WS_TFG) + (size_t)f * MM * ND;
    const float* fslab = fault + (size_t)f * MM * ND;
    int n4 = t * 4;
    for (int m = m0; m < m1; m++) {
      float4 tv = *(const float4*)(theta_ + m * ND + n4);
      float4 fl = *(const float4*)(fslab + (size_t)m * ND + n4);
      float c0 = clamp1(tv.x), c1 = clamp1(tv.y), c2 = clamp1(tv.z), c3 = clamp1(tv.w);
      float z0 = fabsf(c0), z1 = fabsf(c1), z2 = fabsf(c2), z3 = fabsf(c3);
      float w0 = (z0 < 0.01f ? 0.f : c0) * fl.x;
      float w1 = (z1 < 0.01f ? 0.f : c1) * fl.y;
      float w2 = (z2 < 0.01f ? 0.f : c2) * fl.z;
      float w3 = (z3 < 0.01f ? 0.f : c3) * fl.w;
      uint4 o;
      o.x = (f2b(z0) << 16) | f2b(w0);
      o.y = (f2b(z1) << 16) | f2b(w1);
      o.z = (f2b(z2) << 16) | f2b(w2);
      o.w = (f2b(z3) << 16) | f2b(w3);
      *(uint4*)(tfg + (size_t)m * ND + n4) = o;
    }
  } else if (bid < 1024) {
    // ======= ablob role: bf16 A-frags in MFMA order + AA/BB =======
    int bb = bid - 512;
    int kc = bb & 31, fv = bb >> 5;
    if (t < 32) {
      int m = kc * 32 + t;
      float c0 = clamp1(coeff_neg[m]);
      float c1 = clamp1(coeff_neg[MM + m]);
      beta_l[t] = ((c1 + gum_neg[MM + m]) > (c0 + gum_neg[m])) ? 1.f : 0.f;
    }
    __syncthreads();
    int em = t >> 6, l = t & 63;
    int e = em * 16 + (l & 15);
    int g = (l >> 4) & 3;
    int kk = kc * 32 + g * 4;
    const float* ap = a + ((size_t)fv * NE + e) * 1024;
    float4 x0 = *(const float4*)(ap + kk);
    float4 x1 = *(const float4*)(ap + kk + 16);
    float xs[8] = {x0.x, x0.y, x0.z, x0.w, x1.x, x1.y, x1.z, x1.w};
    unsigned axp[8], anp[8];
#pragma unroll
    for (int j = 0; j < 8; j++) {
      int mloc = g * 4 + ((j < 4) ? j : 12 + j);
      float x = xs[j];
      float bs = beta_l[mloc];
      float an = (bs != 0.f) ? frcp(1.f + __expf(fmaf(4.f, x, -2.f))) : (1.f - x);
      axp[j] = f2b(x);
      anp[j] = f2b(an);
      la[t][j] = x * x;
      lb[t][j] = an * an;
    }
    uint4 ox = {axp[0] | (axp[1] << 16), axp[2] | (axp[3] << 16),
                axp[4] | (axp[5] << 16), axp[6] | (axp[7] << 16)};
    uint4 on = {anp[0] | (anp[1] << 16), anp[2] | (anp[3] << 16),
                anp[4] | (anp[5] << 16), anp[6] | (anp[7] << 16)};
    size_t bidx = ((size_t)(fv * 32 + kc) * 4 + em) * 64 + l;
    ((uint4*)(ws + WS_AXB))[bidx] = ox;
    ((uint4*)(ws + WS_ANB))[bidx] = on;
    __syncthreads();
    if (t < 32) {
      int g2 = (t >> 2) & 3, j2 = (t & 3) + 4 * (t >> 4);
      float sa = 0.f, sb = 0.f;
#pragma unroll
      for (int em2 = 0; em2 < 4; em2++)
#pragma unroll
        for (int i = 0; i < 16; i++) {
          sa += la[em2 * 64 + g2 * 16 + i][j2];
          sb += lb[em2 * 64 + g2 * 16 + i][j2];
        }
      ws[WS_AA + fv * 1024 + kc * 32 + t] = sa;
      ws[WS_BB + fv * 1024 + kc * 32 + t] = sb;
    }
  } else {
    // ======= min/abssum role: per-chunk col-min and col-abssum of |tc| =======
    int r = bid - 1024;
    int ng = r & 3, chunk = r >> 2;
    int n = ng * 256 + t;
    int m0 = chunk * 32, m1 = (chunk == 31) ? MM : m0 + 32;
    float mn = 1e30f, sm = 0.f;
    for (int m = m0; m < m1; m++) {
      float g = fabsf(clamp1(theta_[m * ND + n]));
      mn = fminf(mn, g);
      sm += g;
    }
    ws[WS_GMINP + chunk * ND + n] = mn;
    ws[WS_GABSP + chunk * ND + n] = sm;
    if (r == 0 && t == 0) out[POWER_IDX] = 0.f;
  }
}

// ---- fused main: MFMA z & G, inline S, activation, power ----
union U8 { uint4 u; bf16x8 h; };

#define SLOAD(S, MC)                                                       \
  {                                                                        \
    _Pragma("unroll") for (int r = 0; r < 4; r++) {                        \
      size_t row = (size_t)((MC) + mb + r) * ND;                           \
      uA##S[r] = nslab[row + n0 + nin];                                    \
      uB##S[r] = nslab[row + n0 + 16 + nin];                               \
      tgA##S[r] = tslab[row + n0 + nin];                                   \
      tgB##S[r] = tslab[row + n0 + 16 + nin];                              \
    }                                                                      \
  }

#define AABBLOAD(MC)                                                       \
  {                                                                        \
    aa0 = *(const float4*)(AAp + (MC) + mb);                               \
    bb0 = *(const float4*)(BBp + (MC) + mb);                               \
  }

#define SWRITE(P, S)                                                       \
  {                                                                        \
    float aas[4] = {aa0.x, aa0.y, aa0.z, aa0.w};                           \
    float bbs[4] = {bb0.x, bb0.y, bb0.z, bb0.w};                           \
    unsigned wpu[2][4], wnu[2][4], gpu[2][4], gqu[2][4];                   \
    _Pragma("unroll") for (int h = 0; h < 2; h++) {                        \
      _Pragma("unroll") for (int r = 0; r < 4; r++) {                      \
        unsigned tg = h ? tgB##S[r] : tgA##S[r];                           \
        float u = h ? uB##S[r] : uA##S[r];                                 \
        unsigned neg = (tg >> 15) & 1;                                     \
        float aw = b2f(tg & 0x7FFF) * fmaf(u, 0.2f, 0.9f);                 \
        if (h) sacc1 += aw; else sacc0 += aw;                              \
        unsigned wb = f2b(aw);                                             \
        unsigned gb = tg >> 16;                                            \
        wpu[h][r] = neg ? 0u : wb;  wnu[h][r] = neg ? wb : 0u;             \
        gpu[h][r] = neg ? 0u : gb;  gqu[h][r] = neg ? gb : 0u;             \
        float tca = b2f(gb);                                               \
        float t1c = tca * (neg ? bbs[r] : aas[r]);                         \
        if (h) pacc1b += t1c; else pacc1a += t1c;                          \
      }                                                                    \
    }                                                                      \
    _Pragma("unroll") for (int pn = 0; pn < 4; pn++) {                     \
      uint2* pp = (uint2*)&panels[P][pn][0];                               \
      _Pragma("unroll") for (int h = 0; h < 2; h++) {                      \
        const unsigned* v = pn == 0 ? wpu[h] : pn == 1 ? wnu[h]            \
                             : pn == 2 ? gpu[h] : gqu[h];                  \
        int s0i = ((c_s * 2 + h) * 64 + (g0 & 3) * 16 + nin) * 2 + j0q;    \
        pp[s0i] = make_uint2(v[0] | (v[1] << 16), v[2] | (v[3] << 16));    \
      }                                                                    \
    }                                                                      \
  }

#define ALOAD(KS)                                                          \
  {                                                                        \
    _Pragma("unroll") for (int c = 0; c < 2; c++)                          \
      _Pragma("unroll") for (int mi = 0; mi < 2; mi++) {                   \
        size_t bi = ((size_t)(fv * 32 + (KS) * 2 + c) * 4 + eh * 2 + mi) * 64 + l; \
        axr[c][mi] = axbp[bi];                                             \
        anr[c][mi] = anbp[bi];                                             \
      }                                                                    \
  }

#define BMFMA(P)                                                           \
  {                                                                        \
    _Pragma("unroll") for (int c = 0; c < 2; c++) {                        \
      int bslot = (c * 2 + wn) * 64 + l;                                   \
      U8 bwp, bwn, bgp, bgq;                                               \
      bwp.u = panels[P][0][bslot]; bwn.u = panels[P][1][bslot];            \
      bgp.u = panels[P][2][bslot]; bgq.u = panels[P][3][bslot];            \
      _Pragma("unroll") for (int mi = 0; mi < 2; mi++) {                   \
        U8 ax, an; ax.u = axr[c][mi]; an.u = anr[c][mi];                   \
        accz[mi] = __builtin_amdgcn_mfma_f32_16x16x32_bf16(ax.h, bwp.h, accz[mi], 0, 0, 0); \
        accz[mi] = __builtin_amdgcn_mfma_f32_16x16x32_bf16(an.h, bwn.h, accz[mi], 0, 0, 0); \
        accg[mi] = __builtin_amdgcn_mfma_f32_16x16x32_bf16(ax.h, bgp.h, accg[mi], 0, 0, 0); \
        accg[mi] = __builtin_amdgcn_mfma_f32_16x16x32_bf16(an.h, bgq.h, accg[mi], 0, 0, 0); \
      }                                                                    \
    }                                                                      \
  }

#define BAR() __syncthreads()

__global__ __launch_bounds__(256) void k_main(
    const float* __restrict__ noise, const float* __restrict__ ws_c,
    const float* __restrict__ coeff_act, const float* __restrict__ gum_act,
    const float* __restrict__ coeff_neg, const float* __restrict__ gum_neg,
    float* __restrict__ out) {
  const int tid = threadIdx.x;
  const int w4 = tid >> 6, l = tid & 63;
  const int wn = w4 & 1;   // n-half
  const int eh = w4 >> 1;  // e-half
  const int fv = blockIdx.y, f = fv >> 2;
  const int n0 = blockIdx.x * 32;

  __shared__ uint4 panels[2][4][256];
  __shared__ float smin_l[32], gabs_l[32], s_l[32], gsum_l[32];

  if (tid < 32) {
    float mn = 1e30f;
#pragma unroll 8
    for (int c = 0; c < 32; c++) mn = fminf(mn, ws_c[WS_GMINP + c * ND + n0 + tid]);
    smin_l[tid] = mn;
  } else if (tid < 64) {
    int n = tid - 32;
    float s = 0.f;
#pragma unroll 8
    for (int c = 0; c < 32; c++) s += ws_c[WS_GABSP + c * ND + n0 + n];
    gabs_l[n] = s;
  }
  __syncthreads();
  if (tid < 32) {
    float s = 0.1f * frcp(smin_l[tid]);
    s_l[tid] = s;
    gsum_l[tid] = s * gabs_l[tid];
  }

  const int nin = tid & 15;
  const int mb = (tid >> 4) * 4;       // 16 groups x 4 rows = 64 rows
  const int c_s = mb >> 5;
  const int g0 = (mb & 31) >> 2;
  const int j0q = (mb & 31) >> 4;
  const unsigned* tslab = (const unsigned*)(ws_c + WS_TFG) + (size_t)f * MM * ND;
  const float* nslab = noise + (size_t)fv * MM * ND;
  const float* AAp = ws_c + WS_AA + fv * 1024;
  const float* BBp = ws_c + WS_BB + fv * 1024;
  const uint4* axbp = (const uint4*)(ws_c + WS_AXB);
  const uint4* anbp = (const uint4*)(ws_c + WS_ANB);

  float pacc = 0.f, pacc1a = 0.f, pacc1b = 0.f, sacc0 = 0.f, sacc1 = 0.f;
  float uA0[4], uB0[4], uA1[4], uB1[4];
  unsigned tgA0[4], tgB0[4], tgA1[4], tgB1[4];
  float4 aa0, bb0;
  uint4 axr[2][2], anr[2][2];
  f32x4 accz[2] = {};
  f32x4 accg[2] = {};

  // prologue
  AABBLOAD(0);
  SLOAD(0, 0);
  SWRITE(0, 0);          // panel0 <- mc 0
  SLOAD(1, 64);          // set1 <- mc 1
  BAR();

  for (int ks2 = 0; ks2 < 16; ks2 += 2) {
    // ---- body A: compute panel0, write panel1 (regs loaded one iter ago) ----
    ALOAD(ks2);
    AABBLOAD((ks2 + 1) * 64);
    if (ks2 < 14) SLOAD(0, (ks2 + 2) * 64);
    SWRITE(1, 1);
    BMFMA(0);
    BAR();
    // ---- body B: compute panel1, write panel0 ----
    ALOAD(ks2 + 1);
    if (ks2 < 14) {
      AABBLOAD((ks2 + 2) * 64);
      SLOAD(1, (ks2 + 3) * 64);
      SWRITE(0, 0);
    }
    BMFMA(1);
    BAR();
  }

  // ---- epilogue: S reduce, tails, activation, power ----
  float* lds_f = (float*)&panels[0][0][0];
  lds_f[(tid >> 4) * 32 + nin] = sacc0;
  lds_f[(tid >> 4) * 32 + 16 + nin] = sacc1;
  __syncthreads();

  const int n_loc = wn * 16 + (l & 15);
  const int n_e = n0 + n_loc;
  float S = 0.f;
#pragma unroll
  for (int mg = 0; mg < 16; mg++) S += lds_f[mg * 32 + n_loc];

  const float s_ne = s_l[n_loc];
  unsigned tg24 = tslab[(size_t)1024 * ND + n_e];
  unsigned tg25 = tslab[(size_t)1025 * ND + n_e];
  float u24 = nslab[(size_t)1024 * ND + n_e];
  float u25 = nslab[(size_t)1025 * ND + n_e];
  float w24 = b2f(tg24 & 0x7FFF) * fmaf(u24, 0.2f, 0.9f);
  float w25 = b2f(tg25 & 0x7FFF) * fmaf(u25, 0.2f, 0.9f);
  S += w24 + w25;
  const float invS = frcp(S + 1e-10f);

  float cn0 = clamp1(coeff_neg[1024]), cn1 = clamp1(coeff_neg[MM + 1024]);
  const float anb = ((cn1 + gum_neg[MM + 1024]) > (cn0 + gum_neg[1024]))
                        ? frcp(1.f + __expf(2.f)) : 0.f;
  float ca0 = clamp1(coeff_act[n_e]), ca1 = clamp1(coeff_act[ND + n_e]);
  const float alv = ((ca1 + gum_act[ND + n_e]) > (ca0 + gum_act[n_e])) ? 1.f : 0.f;

  unsigned neg24 = (tg24 >> 15) & 1;
  float sel24 = neg24 ? anb : 1.f;
  float ztail = w24 * invS * sel24;
  float gt24 = b2f(tg24 >> 16) * s_ne;
  if (l < 16 && eh == 0) pacc += 64.f * gt24 * sel24 * sel24;  // Term1 m=1024

  const float gsn = gsum_l[n_loc];
  float zsum = 0.f;
#pragma unroll
  for (int mi = 0; mi < 2; mi++) {
#pragma unroll
    for (int r = 0; r < 4; r++) {
      float z = accz[mi][r] * invS + ztail;
      zsum += z;
      pacc += gsn * z * z - 2.f * z * (accg[mi][r] * s_ne);
      float s0v = frcp(1.f + __expf(fmaf(-4.f, z, 2.f)));
      float t1v = 1.f - 2.f * frcp(__expf(2.f * z) + 1.f);
      int e = (eh * 2 + mi) * 16 + ((l >> 4) & 3) * 4 + r;
      out[((size_t)(fv * NE + e)) * ND + n_e] = (alv != 0.f) ? t1v : s0v;
    }
  }
  pacc -= 2.f * zsum * (gt24 * sel24);           // cross-term m=1024
  pacc += s_l[nin] * pacc1a + s_l[16 + nin] * pacc1b;  // Term1 m<1024 (scaled)

  float* red = lds_f + 1024;
  red[tid] = pacc;
  __syncthreads();
  for (int s = 128; s > 0; s >>= 1) {
    if (tid < s) red[tid] += red[tid + s];
    __syncthreads();
  }
  if (tid == 0) atomicAdd(out + POWER_IDX, red[0] * (1.f / 1024.f));
}

extern "C" void kernel_launch(void* const* d_in, const int* in_sizes, int n_in,
                              void* d_out, int out_size, void* d_ws, size_t ws_size,
                              hipStream_t stream) {
  const float* a = (const float*)d_in[0];
  const float* theta_ = (const float*)d_in[1];
  const float* coeff_act = (const float*)d_in[2];
  const float* coeff_neg = (const float*)d_in[3];
  const float* noise_u = (const float*)d_in[4];
  const float* gum_act = (const float*)d_in[5];
  const float* gum_neg = (const float*)d_in[6];
  const float* fault = (const float*)d_in[7];
  float* out = (float*)d_out;
  float* ws = (float*)d_ws;

  k_pre<<<1152, 256, 0, stream>>>(a, theta_, fault, coeff_neg, gum_neg, ws, out);
  k_main<<<dim3(32, 16), 256, 0, stream>>>(noise_u, ws, coeff_act, gum_act,
                                           coeff_neg, gum_neg, out);
}

// Round 8
// 163.202 us; speedup vs baseline: 4.7837x; 1.0682x over previous
//
#include <hip/hip_runtime.h>

typedef float f32x4 __attribute__((ext_vector_type(4)));
typedef short bf16x8 __attribute__((ext_vector_type(8)));

#define NE 64
#define ND 1024
#define MM 1026

// ws float offsets
#define WS_AA    1642504
#define WS_BB    1658888
#define WS_TFG   1675272
#define WS_AXB   5877768
#define WS_ANB   6402056
#define POWER_IDX 1048576

__device__ __forceinline__ float frcp(float x) { return __builtin_amdgcn_rcpf(x); }
__device__ __forceinline__ unsigned f2b(float x) {  // f32 -> bf16 (RNE), low 16
  unsigned u = __float_as_uint(x);
  u += 0x7FFF + ((u >> 16) & 1);
  return u >> 16;
}
__device__ __forceinline__ float b2f(unsigned b) { return __uint_as_float(b << 16); }
__device__ __forceinline__ float clamp1(float x) { return fminf(fmaxf(x, -1.f), 1.f); }

// ---- k_pre: 1024 tf-role + 512 ablob-role + 4 tf-tail blocks ----
__global__ __launch_bounds__(256) void k_pre(
    const float* __restrict__ a, const float* __restrict__ theta_,
    const float* __restrict__ fault, const float* __restrict__ coeff_neg,
    const float* __restrict__ gum_neg, float* __restrict__ ws,
    float* __restrict__ out) {
  int bid = blockIdx.x, t = threadIdx.x;
  __shared__ float la[256][8];
  __shared__ float lb[256][8];
  __shared__ float beta_l[32];

  if (bid < 1024) {
    // ======= tf role: tfg = (bf16(|tc|)<<16) | bf16(tc_zeroed*fault), 4 rows =======
    int f = bid >> 8, chunk = bid & 255;
    int m0 = chunk * 4;
    unsigned* tfg = (unsigned*)(ws + WS_TFG) + (size_t)f * MM * ND;
    const float* fslab = fault + (size_t)f * MM * ND;
    int n4 = t * 4;
#pragma unroll
    for (int r = 0; r < 4; r++) {
      int m = m0 + r;
      float4 tv = *(const float4*)(theta_ + m * ND + n4);
      float4 fl = *(const float4*)(fslab + (size_t)m * ND + n4);
      float c0 = clamp1(tv.x), c1 = clamp1(tv.y), c2 = clamp1(tv.z), c3 = clamp1(tv.w);
      float z0 = fabsf(c0), z1 = fabsf(c1), z2 = fabsf(c2), z3 = fabsf(c3);
      float w0 = (z0 < 0.01f ? 0.f : c0) * fl.x;
      float w1 = (z1 < 0.01f ? 0.f : c1) * fl.y;
      float w2 = (z2 < 0.01f ? 0.f : c2) * fl.z;
      float w3 = (z3 < 0.01f ? 0.f : c3) * fl.w;
      uint4 o;
      o.x = (f2b(z0) << 16) | f2b(w0);
      o.y = (f2b(z1) << 16) | f2b(w1);
      o.z = (f2b(z2) << 16) | f2b(w2);
      o.w = (f2b(z3) << 16) | f2b(w3);
      *(uint4*)(tfg + (size_t)m * ND + n4) = o;
    }
    if (bid == 0 && t == 0) out[POWER_IDX] = 0.f;
  } else if (bid < 1536) {
    // ======= ablob role: bf16 A-frags in MFMA order + AA/BB =======
    int bb = bid - 1024;
    int kc = bb & 31, fv = bb >> 5;
    if (t < 32) {
      int m = kc * 32 + t;
      float c0 = clamp1(coeff_neg[m]);
      float c1 = clamp1(coeff_neg[MM + m]);
      beta_l[t] = ((c1 + gum_neg[MM + m]) > (c0 + gum_neg[m])) ? 1.f : 0.f;
    }
    __syncthreads();
    int em = t >> 6, l = t & 63;
    int e = em * 16 + (l & 15);
    int g = (l >> 4) & 3;
    int kk = kc * 32 + g * 4;
    const float* ap = a + ((size_t)fv * NE + e) * 1024;
    float4 x0 = *(const float4*)(ap + kk);
    float4 x1 = *(const float4*)(ap + kk + 16);
    float xs[8] = {x0.x, x0.y, x0.z, x0.w, x1.x, x1.y, x1.z, x1.w};
    unsigned axp[8], anp[8];
#pragma unroll
    for (int j = 0; j < 8; j++) {
      int mloc = g * 4 + ((j < 4) ? j : 12 + j);
      float x = xs[j];
      float bs = beta_l[mloc];
      float an = (bs != 0.f) ? frcp(1.f + __expf(fmaf(4.f, x, -2.f))) : (1.f - x);
      axp[j] = f2b(x);
      anp[j] = f2b(an);
      la[t][j] = x * x;
      lb[t][j] = an * an;
    }
    uint4 ox = {axp[0] | (axp[1] << 16), axp[2] | (axp[3] << 16),
                axp[4] | (axp[5] << 16), axp[6] | (axp[7] << 16)};
    uint4 on = {anp[0] | (anp[1] << 16), anp[2] | (anp[3] << 16),
                anp[4] | (anp[5] << 16), anp[6] | (anp[7] << 16)};
    size_t bidx = ((size_t)(fv * 32 + kc) * 4 + em) * 64 + l;
    ((uint4*)(ws + WS_AXB))[bidx] = ox;
    ((uint4*)(ws + WS_ANB))[bidx] = on;
    __syncthreads();
    if (t < 32) {
      int g2 = (t >> 2) & 3, j2 = (t & 3) + 4 * (t >> 4);
      float sa = 0.f, sb = 0.f;
#pragma unroll
      for (int em2 = 0; em2 < 4; em2++)
#pragma unroll
        for (int i = 0; i < 16; i++) {
          sa += la[em2 * 64 + g2 * 16 + i][j2];
          sb += lb[em2 * 64 + g2 * 16 + i][j2];
        }
      ws[WS_AA + fv * 1024 + kc * 32 + t] = sa;
      ws[WS_BB + fv * 1024 + kc * 32 + t] = sb;
    }
  } else {
    // ======= tf tail: rows 1024,1025 for one f =======
    int f = bid - 1536;
    unsigned* tfg = (unsigned*)(ws + WS_TFG) + (size_t)f * MM * ND;
    const float* fslab = fault + (size_t)f * MM * ND;
    int n4 = t * 4;
#pragma unroll
    for (int r = 0; r < 2; r++) {
      int m = 1024 + r;
      float4 tv = *(const float4*)(theta_ + m * ND + n4);
      float4 fl = *(const float4*)(fslab + (size_t)m * ND + n4);
      float c0 = clamp1(tv.x), c1 = clamp1(tv.y), c2 = clamp1(tv.z), c3 = clamp1(tv.w);
      float z0 = fabsf(c0), z1 = fabsf(c1), z2 = fabsf(c2), z3 = fabsf(c3);
      float w0 = (z0 < 0.01f ? 0.f : c0) * fl.x;
      float w1 = (z1 < 0.01f ? 0.f : c1) * fl.y;
      float w2 = (z2 < 0.01f ? 0.f : c2) * fl.z;
      float w3 = (z3 < 0.01f ? 0.f : c3) * fl.w;
      uint4 o;
      o.x = (f2b(z0) << 16) | f2b(w0);
      o.y = (f2b(z1) << 16) | f2b(w1);
      o.z = (f2b(z2) << 16) | f2b(w2);
      o.w = (f2b(z3) << 16) | f2b(w3);
      *(uint4*)(tfg + (size_t)m * ND + n4) = o;
    }
  }
}

// ---- fused main: MFMA z & G, inline S/colmin/colabs, activation, power ----
union U8 { uint4 u; bf16x8 h; };

#define SLOAD(S, MC)                                                       \
  {                                                                        \
    _Pragma("unroll") for (int r = 0; r < 4; r++) {                        \
      size_t row = (size_t)((MC) + mb + r) * ND;                           \
      uA##S[r] = __builtin_nontemporal_load(nslab + row + n0 + nin);       \
      uB##S[r] = __builtin_nontemporal_load(nslab + row + n0 + 16 + nin);  \
      tgA##S[r] = tslab[row + n0 + nin];                                   \
      tgB##S[r] = tslab[row + n0 + 16 + nin];                              \
    }                                                                      \
  }

#define AABBLOAD(MC)                                                       \
  {                                                                        \
    aa0 = *(const float4*)(AAp + (MC) + mb);                               \
    bb0 = *(const float4*)(BBp + (MC) + mb);                               \
  }

#define SWRITE(P, S)                                                       \
  {                                                                        \
    float aas[4] = {aa0.x, aa0.y, aa0.z, aa0.w};                           \
    float bbs[4] = {bb0.x, bb0.y, bb0.z, bb0.w};                           \
    unsigned wpu[2][4], wnu[2][4], gpu[2][4], gqu[2][4];                   \
    _Pragma("unroll") for (int h = 0; h < 2; h++) {                        \
      _Pragma("unroll") for (int r = 0; r < 4; r++) {                      \
        unsigned tg = h ? tgB##S[r] : tgA##S[r];                           \
        float u = h ? uB##S[r] : uA##S[r];                                 \
        unsigned neg = (tg >> 15) & 1;                                     \
        float aw = b2f(tg & 0x7FFF) * fmaf(u, 0.2f, 0.9f);                 \
        if (h) sacc1 += aw; else sacc0 += aw;                              \
        unsigned wb = f2b(aw);                                             \
        unsigned gb = tg >> 16;                                            \
        wpu[h][r] = neg ? 0u : wb;  wnu[h][r] = neg ? wb : 0u;             \
        gpu[h][r] = neg ? 0u : gb;  gqu[h][r] = neg ? gb : 0u;             \
        float tca = b2f(gb);                                               \
        float t1c = tca * (neg ? bbs[r] : aas[r]);                         \
        if (h) { pacc1b += t1c; mnacc1 = fminf(mnacc1, tca); gsacc1 += tca; } \
        else   { pacc1a += t1c; mnacc0 = fminf(mnacc0, tca); gsacc0 += tca; } \
      }                                                                    \
    }                                                                      \
    _Pragma("unroll") for (int pn = 0; pn < 4; pn++) {                     \
      uint2* pp = (uint2*)&panels[P][pn][0];                               \
      _Pragma("unroll") for (int h = 0; h < 2; h++) {                      \
        const unsigned* v = pn == 0 ? wpu[h] : pn == 1 ? wnu[h]            \
                             : pn == 2 ? gpu[h] : gqu[h];                  \
        int s0i = ((c_s * 2 + h) * 64 + (g0 & 3) * 16 + nin) * 2 + j0q;    \
        pp[s0i] = make_uint2(v[0] | (v[1] << 16), v[2] | (v[3] << 16));    \
      }                                                                    \
    }                                                                      \
  }

#define ALOAD(KS)                                                          \
  {                                                                        \
    _Pragma("unroll") for (int c = 0; c < 2; c++)                          \
      _Pragma("unroll") for (int mi = 0; mi < 2; mi++) {                   \
        size_t bi = ((size_t)(fv * 32 + (KS) * 2 + c) * 4 + eh * 2 + mi) * 64 + l; \
        axr[c][mi] = axbp[bi];                                             \
        anr[c][mi] = anbp[bi];                                             \
      }                                                                    \
  }

#define BMFMA(P)                                                           \
  {                                                                        \
    _Pragma("unroll") for (int c = 0; c < 2; c++) {                        \
      int bslot = (c * 2 + wn) * 64 + l;                                   \
      U8 bwp, bwn, bgp, bgq;                                               \
      bwp.u = panels[P][0][bslot]; bwn.u = panels[P][1][bslot];            \
      bgp.u = panels[P][2][bslot]; bgq.u = panels[P][3][bslot];            \
      _Pragma("unroll") for (int mi = 0; mi < 2; mi++) {                   \
        U8 ax, an; ax.u = axr[c][mi]; an.u = anr[c][mi];                   \
        accz[mi] = __builtin_amdgcn_mfma_f32_16x16x32_bf16(ax.h, bwp.h, accz[mi], 0, 0, 0); \
        accz[mi] = __builtin_amdgcn_mfma_f32_16x16x32_bf16(an.h, bwn.h, accz[mi], 0, 0, 0); \
        accg[mi] = __builtin_amdgcn_mfma_f32_16x16x32_bf16(ax.h, bgp.h, accg[mi], 0, 0, 0); \
        accg[mi] = __builtin_amdgcn_mfma_f32_16x16x32_bf16(an.h, bgq.h, accg[mi], 0, 0, 0); \
      }                                                                    \
    }                                                                      \
  }

#define BAR() __syncthreads()

__global__ __launch_bounds__(256) void k_main(
    const float* __restrict__ noise, const float* __restrict__ ws_c,
    const float* __restrict__ coeff_act, const float* __restrict__ gum_act,
    const float* __restrict__ coeff_neg, const float* __restrict__ gum_neg,
    float* __restrict__ out) {
  const int tid = threadIdx.x;
  const int w4 = tid >> 6, l = tid & 63;
  const int wn = w4 & 1;   // n-half
  const int eh = w4 >> 1;  // e-half
  const int fv = blockIdx.y, f = fv >> 2;
  const int n0 = blockIdx.x * 32;

  __shared__ uint4 panels[2][4][256];

  const int nin = tid & 15;
  const int mb = (tid >> 4) * 4;       // 16 groups x 4 rows = 64 rows
  const int c_s = mb >> 5;
  const int g0 = (mb & 31) >> 2;
  const int j0q = (mb & 31) >> 4;
  const unsigned* tslab = (const unsigned*)(ws_c + WS_TFG) + (size_t)f * MM * ND;
  const float* nslab = noise + (size_t)fv * MM * ND;
  const float* AAp = ws_c + WS_AA + fv * 1024;
  const float* BBp = ws_c + WS_BB + fv * 1024;
  const uint4* axbp = (const uint4*)(ws_c + WS_AXB);
  const uint4* anbp = (const uint4*)(ws_c + WS_ANB);

  float pacc = 0.f, pacc1a = 0.f, pacc1b = 0.f, sacc0 = 0.f, sacc1 = 0.f;
  float mnacc0 = 1e30f, mnacc1 = 1e30f, gsacc0 = 0.f, gsacc1 = 0.f;
  float uA0[4], uB0[4], uA1[4], uB1[4];
  unsigned tgA0[4], tgB0[4], tgA1[4], tgB1[4];
  float4 aa0, bb0;
  uint4 axr[2][2], anr[2][2];
  f32x4 accz[2] = {};
  f32x4 accg[2] = {};

  // prologue
  AABBLOAD(0);
  SLOAD(0, 0);
  SWRITE(0, 0);          // panel0 <- mc 0
  SLOAD(1, 64);          // set1 <- mc 1
  BAR();

  for (int ks2 = 0; ks2 < 16; ks2 += 2) {
    // ---- body A: compute panel0, write panel1 (regs loaded one iter ago) ----
    ALOAD(ks2);
    AABBLOAD((ks2 + 1) * 64);
    if (ks2 < 14) SLOAD(0, (ks2 + 2) * 64);
    SWRITE(1, 1);
    BMFMA(0);
    BAR();
    // ---- body B: compute panel1, write panel0 ----
    ALOAD(ks2 + 1);
    if (ks2 < 14) {
      AABBLOAD((ks2 + 2) * 64);
      SLOAD(1, (ks2 + 3) * 64);
      SWRITE(0, 0);
    }
    BMFMA(1);
    BAR();
  }

  // ---- epilogue: reduces (S, colmin, colabs, Term1), tails, activation, power ----
  float* lds_f = (float*)&panels[0][0][0];
  const int gi_ = (tid >> 4) * 32;
  lds_f[gi_ + nin] = sacc0;           lds_f[gi_ + 16 + nin] = sacc1;
  lds_f[512 + gi_ + nin] = mnacc0;    lds_f[512 + gi_ + 16 + nin] = mnacc1;
  lds_f[1024 + gi_ + nin] = gsacc0;   lds_f[1024 + gi_ + 16 + nin] = gsacc1;
  lds_f[1536 + gi_ + nin] = pacc1a;   lds_f[1536 + gi_ + 16 + nin] = pacc1b;
  __syncthreads();

  const int n_loc = wn * 16 + (l & 15);
  const int n_e = n0 + n_loc;
  float S = 0.f, MN = 1e30f, GS = 0.f;
#pragma unroll
  for (int mg = 0; mg < 16; mg++) {
    S += lds_f[mg * 32 + n_loc];
    MN = fminf(MN, lds_f[512 + mg * 32 + n_loc]);
    GS += lds_f[1024 + mg * 32 + n_loc];
  }

  unsigned tg24 = tslab[(size_t)1024 * ND + n_e];
  unsigned tg25 = tslab[(size_t)1025 * ND + n_e];
  float u24 = nslab[(size_t)1024 * ND + n_e];
  float u25 = nslab[(size_t)1025 * ND + n_e];
  float w24 = b2f(tg24 & 0x7FFF) * fmaf(u24, 0.2f, 0.9f);
  float w25 = b2f(tg25 & 0x7FFF) * fmaf(u25, 0.2f, 0.9f);
  S += w24 + w25;
  const float invS = frcp(S + 1e-10f);

  float tc24a = b2f(tg24 >> 16), tc25a = b2f(tg25 >> 16);
  MN = fminf(MN, fminf(tc24a, tc25a));
  GS += tc24a + tc25a;
  const float s_ne = 0.1f * frcp(MN);
  const float gsn = s_ne * GS;

  float cn0 = clamp1(coeff_neg[1024]), cn1 = clamp1(coeff_neg[MM + 1024]);
  const float anb = ((cn1 + gum_neg[MM + 1024]) > (cn0 + gum_neg[1024]))
                        ? frcp(1.f + __expf(2.f)) : 0.f;
  float ca0 = clamp1(coeff_act[n_e]), ca1 = clamp1(coeff_act[ND + n_e]);
  const float alv = ((ca1 + gum_act[ND + n_e]) > (ca0 + gum_act[n_e])) ? 1.f : 0.f;

  unsigned neg24 = (tg24 >> 15) & 1;
  float sel24 = neg24 ? anb : 1.f;
  float ztail = w24 * invS * sel24;
  float gt24 = tc24a * s_ne;
  // Term1: m=1024 (once per col) + m<1024 reduce (once per col), flagged threads only
  if (eh == 0 && ((l >> 4) & 3) == 0) {
    float P1 = 0.f;
#pragma unroll
    for (int mg = 0; mg < 16; mg++) P1 += lds_f[1536 + mg * 32 + n_loc];
    pacc += s_ne * P1 + 64.f * gt24 * sel24 * sel24;
  }

  float zsum = 0.f;
#pragma unroll
  for (int mi = 0; mi < 2; mi++) {
#pragma unroll
    for (int r = 0; r < 4; r++) {
      float z = accz[mi][r] * invS + ztail;
      zsum += z;
      pacc += gsn * z * z - 2.f * z * (accg[mi][r] * s_ne);
      float s0v = frcp(1.f + __expf(fmaf(-4.f, z, 2.f)));
      float t1v = 1.f - 2.f * frcp(__expf(2.f * z) + 1.f);
      int e = (eh * 2 + mi) * 16 + ((l >> 4) & 3) * 4 + r;
      out[((size_t)(fv * NE + e)) * ND + n_e] = (alv != 0.f) ? t1v : s0v;
    }
  }
  pacc -= 2.f * zsum * (gt24 * sel24);           // cross-term m=1024

  float* red = lds_f + 2048;
  red[tid] = pacc;
  __syncthreads();
  for (int s = 128; s > 0; s >>= 1) {
    if (tid < s) red[tid] += red[tid + s];
    __syncthreads();
  }
  if (tid == 0) atomicAdd(out + POWER_IDX, red[0] * (1.f / 1024.f));
}

extern "C" void kernel_launch(void* const* d_in, const int* in_sizes, int n_in,
                              void* d_out, int out_size, void* d_ws, size_t ws_size,
                              hipStream_t stream) {
  const float* a = (const float*)d_in[0];
  const float* theta_ = (const float*)d_in[1];
  const float* coeff_act = (const float*)d_in[2];
  const float* coeff_neg = (const float*)d_in[3];
  const float* noise_u = (const float*)d_in[4];
  const float* gum_act = (const float*)d_in[5];
  const float* gum_neg = (const float*)d_in[6];
  const float* fault = (const float*)d_in[7];
  float* out = (float*)d_out;
  float* ws = (float*)d_ws;

  k_pre<<<1540, 256, 0, stream>>>(a, theta_, fault, coeff_neg, gum_neg, ws, out);
  k_main<<<dim3(32, 16), 256, 0, stream>>>(noise_u, ws, coeff_act, gum_act,
                                           coeff_neg, gum_neg, out);
}